// Round 5
// baseline (301.785 us; speedup 1.0000x reference)
//
#include <hip/hip_runtime.h>

#define EMBED 768
#define NH 12
#define HD 64
#define SEQ 4096
#define BATCH 2
#define MROWS (BATCH * SEQ)   // 8192
#define N3E (3 * EMBED)       // 2304

typedef short bf16x8 __attribute__((ext_vector_type(8)));  // 8 bf16 = 4 VGPRs
typedef float fx4 __attribute__((ext_vector_type(4)));     // MFMA C/D 16x16
typedef float f32x16 __attribute__((ext_vector_type(16))); // MFMA C/D 32x32
typedef unsigned short ushort_t;
typedef unsigned short us4 __attribute__((ext_vector_type(4)));  // 8B packed

#if __has_builtin(__builtin_amdgcn_exp2f)
#define EXP2F(x) __builtin_amdgcn_exp2f(x)
#else
#define EXP2F(x) exp2f(x)
#endif

// Q pre-scale: (1/sqrt(64)) * log2(e)  -> softmax runs in exp2 domain
#define QSCALE 0.18033688011112042f

// fp32 -> bf16 round-to-nearest-even
__device__ inline ushort_t f2bf(float f) {
  union { float f; unsigned int u; } x; x.f = f;
  unsigned int r = x.u + 0x7fffu + ((x.u >> 16) & 1u);
  return (ushort_t)(r >> 16);
}

// v_cvt_pk_bf16_f32: D = {lo: bf16(a), hi: bf16(b)} (no builtin on gfx950)
__device__ inline unsigned int cvtpk(float a, float b) {
  unsigned int r;
  asm("v_cvt_pk_bf16_f32 %0, %1, %2" : "=v"(r) : "v"(a), "v"(b));
  return r;
}

// v_permlane32_swap_b32: x[hi lanes] <-> y[lo lanes]
__device__ inline void plswap(unsigned int& x, unsigned int& y) {
  asm("v_permlane32_swap_b32 %0, %1" : "+v"(x), "+v"(y));
}

// ---------------------------------------------------------------------------
// x [M,K] fp32 -> bf16, straight copy. 8 elems/thread.
// ---------------------------------------------------------------------------
__global__ __launch_bounds__(256) void convert_x(const float* __restrict__ in,
                                                 ushort_t* __restrict__ out) {
  int i = (blockIdx.x * 256 + threadIdx.x) * 8;
  float4 a = *(const float4*)(in + i);
  float4 b = *(const float4*)(in + i + 4);
  bf16x8 o;
  o[0] = f2bf(a.x); o[1] = f2bf(a.y); o[2] = f2bf(a.z); o[3] = f2bf(a.w);
  o[4] = f2bf(b.x); o[5] = f2bf(b.y); o[6] = f2bf(b.z); o[7] = f2bf(b.w);
  *(bf16x8*)(out + i) = o;
}

// ---------------------------------------------------------------------------
// W [K,N] fp32 -> W^T [N,K] bf16 via 64x64 LDS tile (stride 65: conflict-free)
// ---------------------------------------------------------------------------
__global__ __launch_bounds__(256) void transpose_w(const float* __restrict__ in,
                                                   ushort_t* __restrict__ out,
                                                   int K, int N) {
  __shared__ float t[64][65];
  const int bn = blockIdx.x * 64, bk = blockIdx.y * 64;
  const int c = threadIdx.x & 63, r0 = threadIdx.x >> 6;
#pragma unroll
  for (int rr = 0; rr < 16; ++rr) {
    int row = rr * 4 + r0;
    t[row][c] = in[(size_t)(bk + row) * N + bn + c];
  }
  __syncthreads();
#pragma unroll
  for (int rr = 0; rr < 16; ++rr) {
    int row = rr * 4 + r0;
    out[(size_t)(bn + row) * K + bk + c] = f2bf(t[c][row]);
  }
}

// ---------------------------------------------------------------------------
// bf16 MFMA GEMM (m97 structure): C[M,N] = A[M,K] @ Bt[N,K]^T + bias.
// 128x128 tile, BK=32, 4 waves x (64x64), global_load_lds width-16 staging,
// XOR-swizzled [m][k-slot] LDS layout.
// SCATTER: N==2304 -> q (pre-scaled QSCALE, [B,H,S,D]) / k ([B,H,S,D]) /
//          v (transposed [B,H,D,S]) bf16 buffers.  else: fp32 [M,N] out.
// ---------------------------------------------------------------------------
template <int N_, int K_, bool SCATTER>
__global__ __launch_bounds__(256) void gemm_mfma(
    const ushort_t* __restrict__ A, const ushort_t* __restrict__ Bt,
    const float* __restrict__ bias, float* __restrict__ outF,
    ushort_t* __restrict__ oq, ushort_t* __restrict__ ok,
    ushort_t* __restrict__ ov) {
  __shared__ __align__(16) ushort_t As[128 * 32];
  __shared__ __align__(16) ushort_t Bs[128 * 32];
  const int tid = threadIdx.x;
  const int w = tid >> 6, lane = tid & 63;
  const int quad = lane >> 4, ln = lane & 15;
  const int bm = blockIdx.y * 128, bn = blockIdx.x * 128;
  const int wm = (w >> 1) * 64, wn = (w & 1) * 64;

  const int sr = lane >> 2;     // row within 16-row chunk
  const int sslot = lane & 3;   // 16B slot within row

  fx4 acc[4][4] = {};

  for (int k0 = 0; k0 < K_; k0 += 32) {
    __syncthreads();
#pragma unroll
    for (int r = 0; r < 2; ++r) {
      const int c = w + r * 4;        // chunk 0..7 (wave-uniform)
      const int m = c * 16 + sr;      // tile row 0..127
      const int kk = k0 + ((sslot ^ (m & 3)) << 3);
      __builtin_amdgcn_global_load_lds(
          (const __attribute__((address_space(1))) unsigned int*)
              (A + (size_t)(bm + m) * K_ + kk),
          (__attribute__((address_space(3))) unsigned int*)(As + c * 512),
          16, 0, 0);
      __builtin_amdgcn_global_load_lds(
          (const __attribute__((address_space(1))) unsigned int*)
              (Bt + (size_t)(bn + m) * K_ + kk),
          (__attribute__((address_space(3))) unsigned int*)(Bs + c * 512),
          16, 0, 0);
    }
    __syncthreads();

    bf16x8 af[4], bfr[4];
#pragma unroll
    for (int i = 0; i < 4; ++i) {
      const int m = wm + i * 16 + ln;
      af[i] = *(const bf16x8*)(As + m * 32 + ((quad ^ (m & 3)) << 3));
    }
#pragma unroll
    for (int j = 0; j < 4; ++j) {
      const int n = wn + j * 16 + ln;
      bfr[j] = *(const bf16x8*)(Bs + n * 32 + ((quad ^ (n & 3)) << 3));
    }
#pragma unroll
    for (int i = 0; i < 4; ++i)
#pragma unroll
      for (int j = 0; j < 4; ++j)
        acc[i][j] = __builtin_amdgcn_mfma_f32_16x16x32_bf16(af[i], bfr[j],
                                                            acc[i][j], 0, 0, 0);
  }

  if (!SCATTER) {
#pragma unroll
    for (int j = 0; j < 4; ++j) {
      const int n = bn + wn + j * 16 + ln;
      const float bv = bias[n];
#pragma unroll
      for (int i = 0; i < 4; ++i) {
        const int m0 = bm + wm + i * 16 + quad * 4;
#pragma unroll
        for (int r = 0; r < 4; ++r)
          outF[(size_t)(m0 + r) * N_ + n] = acc[i][j][r] + bv;
      }
    }
  } else {
    const int t = bn / EMBED;  // 768 % 128 == 0: whole tile in one of q/k/v
#pragma unroll
    for (int j = 0; j < 4; ++j) {
      const int nn = bn + wn + j * 16 + ln;
      const int rem = nn - t * EMBED;
      const int h = rem >> 6, d = rem & 63;
      const float bv = bias[nn];
#pragma unroll
      for (int i = 0; i < 4; ++i) {
        const int m0 = bm + wm + i * 16 + quad * 4;
#pragma unroll
        for (int r = 0; r < 4; ++r) {
          const int m = m0 + r;
          const int b_ = m >> 12, s = m & 4095;
          const float v = acc[i][j][r] + bv;
          if (t == 0)
            oq[((size_t)(b_ * NH + h) * SEQ + s) * HD + d] = f2bf(v * QSCALE);
          else if (t == 1)
            ok[((size_t)(b_ * NH + h) * SEQ + s) * HD + d] = f2bf(v);
          else
            ov[((size_t)(b_ * NH + h) * HD + d) * SEQ + s] = f2bf(v);
        }
      }
    }
  }
}

// ---------------------------------------------------------------------------
// Causal flash attention v6: FULLY WAVE-INDEPENDENT.  1 wave (64 thr) per
// block, ZERO barriers, wave-private K/V double-buffer, counted vmcnt.
//  * R2-R4 evidence: three structures all ~90 us; per-CU cycle accounting
//    shows DS(46%) + MFMA(23%) + VALU(32%) SUMMING to the iteration time ->
//    lockstep phase-serialization from __syncthreads+vmcnt(0) every iter.
//  * v6: each wave owns q-tile PAIR (2p, 2p+1) (64 rows total), KBLK=32.
//    kf/vf ds_reads shared by both q-groups: 8 x b128 feed 16 MFMAs
//    (DS demand halves).  No barrier anywhere; per-wave s_waitcnt vmcnt(8)
//    only (2 tiles in flight, T4).  Waves drift out of phase -> DS/MFMA/
//    VALU overlap ACROSS waves.  MFMA demand at 8 waves/CU ~ 4 pipes ->
//    expect MFMA-bound (~25-30 us) + critical path (longest pair 128 iters).
//  * LDS 16 KB/block -> 10 blocks/CU cap; VGPR<=256 (lb 64,2) -> 8/CU;
//    grid (24,64)=1536 blocks = 6/CU, all co-resident, stride-256 pickup
//    naturally stratifies pair lengths per CU.  XCD = bh%8 preserved.
//  * Tiles: K [32 kr][64 d] (granule swz ^(row&7)); V^T [64 d][32 s]
//    (swz ^((row>>1)&3), 4-way max).  Always-stage clamped tile kt+2 ->
//    uniform vmcnt(8).  lgkmcnt(0)+sched_barrier before re-staging a buffer.
// ---------------------------------------------------------------------------
__global__ __launch_bounds__(64, 2) void flash_mfma(
    const ushort_t* __restrict__ qb, const ushort_t* __restrict__ kb,
    const ushort_t* __restrict__ vb, ushort_t* __restrict__ attn) {
  __shared__ __align__(16) ushort_t Ks[2][32 * 64];  // 4 KB each
  __shared__ __align__(16) ushort_t Vt[2][64 * 32];  // 4 KB each

  const int lane = threadIdx.x;  // 0..63 (single wave)
  const int r32 = lane & 31;     // MFMA row / q-col index
  const int hf = lane >> 5;      // half-lane selector
  const int gk = r32 & 7;        // K swizzle key (128B rows)
  const int gv = (r32 >> 1) & 3; // V swizzle key (64B rows)
  const int rc4 = hf * 4;        // rowcode offset

  const int bh = blockIdx.x;            // 0..23, XCD = bh%8
  const int p = 63 - (int)blockIdx.y;   // pair index (descending length)
  const int kend = 2 * p + 1;           // last 32-wide k-tile (B's diagonal)

  const size_t base = (size_t)bh * SEQ * HD;
  const ushort_t* Qg = qb + base;
  const ushort_t* Kg = kb + base;
  const ushort_t* Vg = vb + base;  // [HD][SEQ]

  // ---- staging geometry (kt-invariant) ----
  // K inst i: row = 8i + (lane>>3) (128B rows), granule (lane&7)^(row&7)
  const int krow_s = lane >> 3;
  const int kg_s = (lane & 7) ^ krow_s;          // row&7 == krow_s
  // V inst i: row = 16i + (lane>>2) (64B rows), granule (lane&3)^((row>>1)&3)
  const int vrow_s = lane >> 2;
  const int vg_s = (lane & 3) ^ ((vrow_s >> 1) & 3);
  const ushort_t* kbase[4];
  const ushort_t* vbase[4];
#pragma unroll
  for (int i = 0; i < 4; ++i) {
    kbase[i] = Kg + i * 512 + krow_s * 64 + kg_s * 8;
    vbase[i] = Vg + (size_t)(16 * i + vrow_s) * SEQ + vg_s * 8;
  }

  // ---- fragment offsets (elements, kt-invariant) ----
  int koff[4], voff[4];
#pragma unroll
  for (int dc = 0; dc < 4; ++dc)
    koff[dc] = r32 * 64 + (((2 * dc + hf) ^ gk) << 3);
#pragma unroll
  for (int vb2 = 0; vb2 < 2; ++vb2)
#pragma unroll
    for (int ch = 0; ch < 2; ++ch)
      voff[vb2 * 2 + ch] =
          (vb2 * 32 + r32) * 32 + (((2 * ch + hf) ^ gv) << 3);

  // ---- Q fragments, both groups (kt-invariant) ----
  bf16x8 qfA[4], qfB[4];
  {
    const ushort_t* qra = Qg + (size_t)(64 * p + r32) * HD;
    const ushort_t* qrb = qra + 32 * HD;
#pragma unroll
    for (int dc = 0; dc < 4; ++dc) {
      qfA[dc] = *(const bf16x8*)(qra + dc * 16 + hf * 8);
      qfB[dc] = *(const bf16x8*)(qrb + dc * 16 + hf * 8);
    }
  }

  auto STAGE = [&](int ks, int buf) {
#pragma unroll
    for (int i = 0; i < 4; ++i) {
      __builtin_amdgcn_global_load_lds(
          (const __attribute__((address_space(1))) unsigned int*)
              (kbase[i] + (size_t)ks * 2048),
          (__attribute__((address_space(3))) unsigned int*)(&Ks[buf][i * 512]),
          16, 0, 0);
      __builtin_amdgcn_global_load_lds(
          (const __attribute__((address_space(1))) unsigned int*)
              (vbase[i] + ks * 32),
          (__attribute__((address_space(3))) unsigned int*)(&Vt[buf][i * 512]),
          16, 0, 0);
    }
  };

  f32x16 oA0 = {}, oA1 = {}, oB0 = {}, oB1 = {};
  float lA = 0.f, lB = 0.f;

  // softmax + pack + PV for one group (s by value; dg = diagonal mask)
  auto smpv = [&](f32x16 s, float& lsum, f32x16& o0, f32x16& o1, bool dg,
                  const bf16x8 (&vf)[4]) {
    if (dg) {
#pragma unroll
      for (int r = 0; r < 16; ++r) {
        const int rowc = (r & 3) + 8 * (r >> 2) + rc4;
        if (rowc > r32) s[r] = -1e30f;
      }
    }
    float e[16];
#pragma unroll
    for (int r = 0; r < 16; ++r) e[r] = EXP2F(s[r]);
    {
      float t0 = ((e[0] + e[1]) + (e[2] + e[3])) +
                 ((e[4] + e[5]) + (e[6] + e[7]));
      float t1 = ((e[8] + e[9]) + (e[10] + e[11])) +
                 ((e[12] + e[13]) + (e[14] + e[15]));
      lsum += t0 + t1;
    }
    // pack 2 chunks (kr 0..15 = regs 0..7, kr 16..31 = regs 8..15)
    bf16x8 pf[2];
#pragma unroll
    for (int ch = 0; ch < 2; ++ch) {
      const int rb = ch * 8;
      unsigned int x0 = cvtpk(e[rb + 0], e[rb + 1]);
      unsigned int x1 = cvtpk(e[rb + 2], e[rb + 3]);
      unsigned int y0 = cvtpk(e[rb + 4], e[rb + 5]);
      unsigned int y1 = cvtpk(e[rb + 6], e[rb + 7]);
      plswap(x0, y0);
      plswap(x1, y1);
      union { unsigned int u[4]; bf16x8 v; } w_;
      w_.u[0] = x0; w_.u[1] = x1; w_.u[2] = y0; w_.u[3] = y1;
      pf[ch] = w_.v;
    }
    __builtin_amdgcn_s_setprio(1);
    o0 = __builtin_amdgcn_mfma_f32_32x32x16_bf16(vf[0], pf[0], o0, 0, 0, 0);
    o1 = __builtin_amdgcn_mfma_f32_32x32x16_bf16(vf[2], pf[0], o1, 0, 0, 0);
    o0 = __builtin_amdgcn_mfma_f32_32x32x16_bf16(vf[1], pf[1], o0, 0, 0, 0);
    o1 = __builtin_amdgcn_mfma_f32_32x32x16_bf16(vf[3], pf[1], o1, 0, 0, 0);
    __builtin_amdgcn_s_setprio(0);
  };

  // ---- prologue: stage tiles 0,1 ----
  STAGE(0, 0);
  STAGE(1, 1);

  for (int kt = 0; kt <= kend; ++kt) {
    const int cur = kt & 1;
    asm volatile("s_waitcnt vmcnt(8)" ::: "memory");  // tile kt landed
    bf16x8 kf[4], vf[4];
#pragma unroll
    for (int dc = 0; dc < 4; ++dc)
      kf[dc] = *(const bf16x8*)(&Ks[cur][koff[dc]]);
#pragma unroll
    for (int j = 0; j < 4; ++j)
      vf[j] = *(const bf16x8*)(&Vt[cur][voff[j]]);

    if (kt < kend) {  // both groups active (hot path)
      f32x16 sA = {}, sB = {};
#pragma unroll
      for (int dc = 0; dc < 4; ++dc) {
        sB = __builtin_amdgcn_mfma_f32_32x32x16_bf16(kf[dc], qfB[dc], sB, 0, 0, 0);
        sA = __builtin_amdgcn_mfma_f32_32x32x16_bf16(kf[dc], qfA[dc], sA, 0, 0, 0);
      }
      smpv(sA, lA, oA0, oA1, kt == kend - 1, vf);
      smpv(sB, lB, oB0, oB1, false, vf);
    } else {  // last tile: B solo, diagonal
      f32x16 sB = {};
#pragma unroll
      for (int dc = 0; dc < 4; ++dc)
        sB = __builtin_amdgcn_mfma_f32_32x32x16_bf16(kf[dc], qfB[dc], sB, 0, 0, 0);
      smpv(sB, lB, oB0, oB1, true, vf);
    }

    // re-stage buf[kt&1] with tile kt+2 (clamped: keeps vmcnt(8) uniform)
    asm volatile("s_waitcnt lgkmcnt(0)" ::: "memory");
    __builtin_amdgcn_sched_barrier(0);
    const int ks = (kt + 2 <= kend) ? (kt + 2) : kend;
    STAGE(ks, cur);
  }

  // ---- l reduction (hf pair) + epilogue ----
  lA += __shfl_xor(lA, 32);
  lB += __shfl_xor(lB, 32);
  const float invA = 1.f / lA;
  const float invB = 1.f / lB;
  const int b_ = bh / NH, h = bh % NH;
  ushort_t* orA = attn + (size_t)(b_ * SEQ + 64 * p + r32) * EMBED + h * HD;
  ushort_t* orB = orA + (size_t)32 * EMBED;
#pragma unroll
  for (int vb2 = 0; vb2 < 2; ++vb2)
#pragma unroll
    for (int rq = 0; rq < 4; ++rq) {
      us4 oa, ob;
#pragma unroll
      for (int r = 0; r < 4; ++r) {
        oa[r] = f2bf((vb2 ? oA1 : oA0)[rq * 4 + r] * invA);
        ob[r] = f2bf((vb2 ? oB1 : oB0)[rq * 4 + r] * invB);
      }
      *(us4*)(orA + vb2 * 32 + rq * 8 + rc4) = oa;
      *(us4*)(orB + vb2 * 32 + rq * 8 + rc4) = ob;
    }
}

extern "C" void kernel_launch(void* const* d_in, const int* in_sizes, int n_in,
                              void* d_out, int out_size, void* d_ws,
                              size_t ws_size, hipStream_t stream) {
  const float* x = (const float*)d_in[0];      // [B,S,E]
  const float* w_qkv = (const float*)d_in[1];  // [E,3E]
  const float* b_qkv = (const float*)d_in[2];  // [3E]
  const float* w_out = (const float*)d_in[3];  // [E,E]
  const float* b_out = (const float*)d_in[4];  // [E]
  float* out = (float*)d_out;                  // [B,S,E] fp32

  const size_t per = (size_t)BATCH * NH * SEQ * HD;  // 6291456
  ushort_t* q_buf = (ushort_t*)d_ws;          // [B,H,S,D] (scaled by QSCALE)
  ushort_t* k_buf = q_buf + per;              // [B,H,S,D]
  ushort_t* v_buf = k_buf + per;              // [B,H,D,S] (transposed)
  ushort_t* attn_buf = v_buf + per;           // [B,S,E] bf16
  ushort_t* xb = attn_buf + per;              // [M,E] bf16
  ushort_t* wqkvT = xb + per;                 // [3E,E] bf16
  ushort_t* woutT = wqkvT + (size_t)N3E * EMBED;  // [E,E] bf16

  convert_x<<<(MROWS * EMBED) / 2048, 256, 0, stream>>>(x, xb);
  transpose_w<<<dim3(N3E / 64, EMBED / 64), 256, 0, stream>>>(w_qkv, wqkvT,
                                                              EMBED, N3E);
  transpose_w<<<dim3(EMBED / 64, EMBED / 64), 256, 0, stream>>>(w_out, woutT,
                                                                EMBED, EMBED);

  dim3 g1(N3E / 128, MROWS / 128);  // (18,64)
  gemm_mfma<N3E, EMBED, true><<<g1, 256, 0, stream>>>(
      xb, wqkvT, b_qkv, nullptr, q_buf, k_buf, v_buf);

  dim3 g2(BATCH * NH, 64);  // bh fast (XCD = bh%8); p = 63-y descending
  flash_mfma<<<g2, 64, 0, stream>>>(q_buf, k_buf, v_buf, attn_buf);

  dim3 g3(EMBED / 128, MROWS / 128);  // (6,64)
  gemm_mfma<EMBED, EMBED, false><<<g3, 256, 0, stream>>>(
      attn_buf, woutT, b_out, out, nullptr, nullptr, nullptr);
}

// Round 6
// 283.619 us; speedup vs baseline: 1.0640x; 1.0640x over previous
//
#include <hip/hip_runtime.h>

#define EMBED 768
#define NH 12
#define HD 64
#define SEQ 4096
#define BATCH 2
#define MROWS (BATCH * SEQ)   // 8192
#define N3E (3 * EMBED)       // 2304

typedef short bf16x8 __attribute__((ext_vector_type(8)));  // 8 bf16 = 4 VGPRs
typedef float fx4 __attribute__((ext_vector_type(4)));     // MFMA C/D 16x16
typedef unsigned short ushort_t;
typedef unsigned short us4 __attribute__((ext_vector_type(4)));  // 8B packed

#if __has_builtin(__builtin_amdgcn_exp2f)
#define EXP2F(x) __builtin_amdgcn_exp2f(x)
#else
#define EXP2F(x) exp2f(x)
#endif

// Q pre-scale: (1/sqrt(64)) * log2(e)  -> softmax runs in exp2 domain
#define QSCALE 0.18033688011112042f

// fp32 -> bf16 round-to-nearest-even
__device__ inline ushort_t f2bf(float f) {
  union { float f; unsigned int u; } x; x.f = f;
  unsigned int r = x.u + 0x7fffu + ((x.u >> 16) & 1u);
  return (ushort_t)(r >> 16);
}

// ---------------------------------------------------------------------------
// x [M,K] fp32 -> bf16, straight copy. 8 elems/thread.
// ---------------------------------------------------------------------------
__global__ __launch_bounds__(256) void convert_x(const float* __restrict__ in,
                                                 ushort_t* __restrict__ out) {
  int i = (blockIdx.x * 256 + threadIdx.x) * 8;
  float4 a = *(const float4*)(in + i);
  float4 b = *(const float4*)(in + i + 4);
  bf16x8 o;
  o[0] = f2bf(a.x); o[1] = f2bf(a.y); o[2] = f2bf(a.z); o[3] = f2bf(a.w);
  o[4] = f2bf(b.x); o[5] = f2bf(b.y); o[6] = f2bf(b.z); o[7] = f2bf(b.w);
  *(bf16x8*)(out + i) = o;
}

// ---------------------------------------------------------------------------
// W [K,N] fp32 -> W^T [N,K] bf16 via 64x64 LDS tile (stride 65: conflict-free)
// ---------------------------------------------------------------------------
__global__ __launch_bounds__(256) void transpose_w(const float* __restrict__ in,
                                                   ushort_t* __restrict__ out,
                                                   int K, int N) {
  __shared__ float t[64][65];
  const int bn = blockIdx.x * 64, bk = blockIdx.y * 64;
  const int c = threadIdx.x & 63, r0 = threadIdx.x >> 6;
#pragma unroll
  for (int rr = 0; rr < 16; ++rr) {
    int row = rr * 4 + r0;
    t[row][c] = in[(size_t)(bk + row) * N + bn + c];
  }
  __syncthreads();
#pragma unroll
  for (int rr = 0; rr < 16; ++rr) {
    int row = rr * 4 + r0;
    out[(size_t)(bn + row) * K + bk + c] = f2bf(t[c][row]);
  }
}

// ---------------------------------------------------------------------------
// bf16 MFMA GEMM v2 (256x256 counted-vmcnt deep pipeline, T3+T4+T5):
//   C[M,N] = A[M,K] @ Bt[N,K]^T + bias.
//  * BK=32, FOUR LDS buffers (4 x (A 16K + B 16K) = 128 KiB): tile t staged
//    3 K-steps ahead -> s_waitcnt vmcnt(8) ONCE per step (tiles t+1,t+2 stay
//    in flight across barriers; never drains to 0 in the loop).
//  * 512 thr = 8 waves (2M x 4N), per-wave 128x64 output, acc[8][4].
//  * 4 quadrant-phases per K-step: {ds_read frags | 1 stage-load of tile
//    t+3 -> s_barrier -> setprio(1) -> 8 MFMA -> setprio(0) -> s_barrier}.
//    Raw s_barrier (no __syncthreads vmcnt(0) drain).
//  * LDS: linear dest + inverse-XOR-swizzled global source + XOR-swizzled
//    ds_read (granule ^= row&3): <=4-way read conflicts.
//  * Race audit: tile t+3 -> buf[(t+3)&3] = buf[(t-1)&3]; last reader of
//    t-1 passed step t-1's closing barrier before any t+3 stage issues.
//    Step-entry vmcnt(8)+barrier orders DMA-land vs all waves' reads.
// SCATTER epilogue identical to v1 (q scaled / k / v-transposed bf16).
// ---------------------------------------------------------------------------
template <int N_, int K_, bool SCATTER>
__global__ __launch_bounds__(512) void gemm_256(
    const ushort_t* __restrict__ A, const ushort_t* __restrict__ Bt,
    const float* __restrict__ bias, float* __restrict__ outF,
    ushort_t* __restrict__ oq, ushort_t* __restrict__ ok,
    ushort_t* __restrict__ ov) {
  constexpr int NT = K_ / 32;  // 24 for K=768 (must be >= 3)
  __shared__ __align__(16) ushort_t As[4][256 * 32];  // 64 KiB
  __shared__ __align__(16) ushort_t Bs[4][256 * 32];  // 64 KiB
  const int tid = threadIdx.x;
  const int wid = tid >> 6, lane = tid & 63;
  const int quad = lane >> 4, ln = lane & 15;
  const int wr = wid >> 2, wc = wid & 3;  // wave grid 2(M) x 4(N)
  const int bm = blockIdx.y * 256, bn = blockIdx.x * 256;

  // ---- staging geometry: inst a covers rows a*128 + wid*16 + (lane>>2) ----
  const int srow = lane >> 2;                   // row within 16-row group
  const int sgr = (lane & 3) ^ (srow & 3);      // inverse-swizzled src granule
  const ushort_t* pA[2];
  const ushort_t* pB[2];
#pragma unroll
  for (int a = 0; a < 2; ++a) {
    pA[a] = A + (size_t)(bm + a * 128 + wid * 16 + srow) * K_ + (sgr << 3);
    pB[a] = Bt + (size_t)(bn + a * 128 + wid * 16 + srow) * K_ + (sgr << 3);
  }
  const int ldst0 = wid * 16 * 32;  // wave-uniform LDS dest (elements)

  // ---- fragment read bases (swizzled granule = quad ^ (row&3)) ----
  const int abase = (wr * 128 + ln) * 32 + ((quad ^ (ln & 3)) << 3);
  const int bbase = (wc * 64 + ln) * 32 + ((quad ^ (ln & 3)) << 3);

  fx4 acc[8][4] = {};

  // ---- prologue: stage tiles 0,1,2 (12 loads/thread outstanding) ----
#pragma unroll
  for (int ti = 0; ti < 3; ++ti) {
#pragma unroll
    for (int a = 0; a < 2; ++a)
      __builtin_amdgcn_global_load_lds(
          (const __attribute__((address_space(1))) unsigned int*)(pA[a] + ti * 32),
          (__attribute__((address_space(3))) unsigned int*)(&As[ti][a * 4096 + ldst0]),
          16, 0, 0);
#pragma unroll
    for (int b = 0; b < 2; ++b)
      __builtin_amdgcn_global_load_lds(
          (const __attribute__((address_space(1))) unsigned int*)(pB[b] + ti * 32),
          (__attribute__((address_space(3))) unsigned int*)(&Bs[ti][b * 4096 + ldst0]),
          16, 0, 0);
  }

#pragma unroll 4
  for (int t = 0; t < NT; ++t) {
    const int buf = t & 3;
    // tile t landed iff <=8 younger loads (t+1,t+2) remain outstanding
    asm volatile("s_waitcnt vmcnt(8)" ::: "memory");
    __builtin_amdgcn_s_barrier();
    const ushort_t* Ab = &As[buf][0];
    const ushort_t* Bb = &Bs[buf][0];
    const int nbuf = (t + 3) & 3;
    const bool st = (t + 3) < NT;
    bf16x8 af[4], b01[2], b23[2];

    // ---- phase 0: quadrant (i 0-3) x (j 0-1) ----
#pragma unroll
    for (int i = 0; i < 4; ++i) af[i] = *(const bf16x8*)(Ab + abase + i * 512);
#pragma unroll
    for (int j = 0; j < 2; ++j) b01[j] = *(const bf16x8*)(Bb + bbase + j * 512);
    if (st)
      __builtin_amdgcn_global_load_lds(
          (const __attribute__((address_space(1))) unsigned int*)(pA[0] + (t + 3) * 32),
          (__attribute__((address_space(3))) unsigned int*)(&As[nbuf][ldst0]),
          16, 0, 0);
    __builtin_amdgcn_s_barrier();
    __builtin_amdgcn_s_setprio(1);
#pragma unroll
    for (int i = 0; i < 4; ++i)
#pragma unroll
      for (int j = 0; j < 2; ++j)
        acc[i][j] = __builtin_amdgcn_mfma_f32_16x16x32_bf16(af[i], b01[j],
                                                            acc[i][j], 0, 0, 0);
    __builtin_amdgcn_s_setprio(0);
    __builtin_amdgcn_s_barrier();

    // ---- phase 1: quadrant (i 0-3) x (j 2-3) ----
#pragma unroll
    for (int j = 0; j < 2; ++j)
      b23[j] = *(const bf16x8*)(Bb + bbase + (2 + j) * 512);
    if (st)
      __builtin_amdgcn_global_load_lds(
          (const __attribute__((address_space(1))) unsigned int*)(pA[1] + (t + 3) * 32),
          (__attribute__((address_space(3))) unsigned int*)(&As[nbuf][4096 + ldst0]),
          16, 0, 0);
    __builtin_amdgcn_s_barrier();
    __builtin_amdgcn_s_setprio(1);
#pragma unroll
    for (int i = 0; i < 4; ++i)
#pragma unroll
      for (int j = 0; j < 2; ++j)
        acc[i][2 + j] = __builtin_amdgcn_mfma_f32_16x16x32_bf16(
            af[i], b23[j], acc[i][2 + j], 0, 0, 0);
    __builtin_amdgcn_s_setprio(0);
    __builtin_amdgcn_s_barrier();

    // ---- phase 2: quadrant (i 4-7) x (j 2-3) ----
#pragma unroll
    for (int i = 0; i < 4; ++i)
      af[i] = *(const bf16x8*)(Ab + abase + (4 + i) * 512);
    if (st)
      __builtin_amdgcn_global_load_lds(
          (const __attribute__((address_space(1))) unsigned int*)(pB[0] + (t + 3) * 32),
          (__attribute__((address_space(3))) unsigned int*)(&Bs[nbuf][ldst0]),
          16, 0, 0);
    __builtin_amdgcn_s_barrier();
    __builtin_amdgcn_s_setprio(1);
#pragma unroll
    for (int i = 0; i < 4; ++i)
#pragma unroll
      for (int j = 0; j < 2; ++j)
        acc[4 + i][2 + j] = __builtin_amdgcn_mfma_f32_16x16x32_bf16(
            af[i], b23[j], acc[4 + i][2 + j], 0, 0, 0);
    __builtin_amdgcn_s_setprio(0);
    __builtin_amdgcn_s_barrier();

    // ---- phase 3: quadrant (i 4-7) x (j 0-1) ----
    if (st)
      __builtin_amdgcn_global_load_lds(
          (const __attribute__((address_space(1))) unsigned int*)(pB[1] + (t + 3) * 32),
          (__attribute__((address_space(3))) unsigned int*)(&Bs[nbuf][4096 + ldst0]),
          16, 0, 0);
    __builtin_amdgcn_s_barrier();
    __builtin_amdgcn_s_setprio(1);
#pragma unroll
    for (int i = 0; i < 4; ++i)
#pragma unroll
      for (int j = 0; j < 2; ++j)
        acc[4 + i][j] = __builtin_amdgcn_mfma_f32_16x16x32_bf16(
            af[i], b01[j], acc[4 + i][j], 0, 0, 0);
    __builtin_amdgcn_s_setprio(0);
    // no trailing barrier: next step entry has vmcnt+barrier
  }

  // ---- epilogue ----
  if (!SCATTER) {
#pragma unroll
    for (int j = 0; j < 4; ++j) {
      const int n = bn + wc * 64 + j * 16 + ln;
      const float bv = bias[n];
#pragma unroll
      for (int i = 0; i < 8; ++i) {
        const int m0 = bm + wr * 128 + i * 16 + quad * 4;
#pragma unroll
        for (int r = 0; r < 4; ++r)
          outF[(size_t)(m0 + r) * N_ + n] = acc[i][j][r] + bv;
      }
    }
  } else {
    const int t3 = bn / EMBED;  // 768 % 256 == 0: whole tile in one of q/k/v
#pragma unroll
    for (int j = 0; j < 4; ++j) {
      const int nn = bn + wc * 64 + j * 16 + ln;
      const int rem = nn - t3 * EMBED;
      const int h = rem >> 6, d = rem & 63;
      const float bv = bias[nn];
#pragma unroll
      for (int i = 0; i < 8; ++i) {
        const int m0 = bm + wr * 128 + i * 16 + quad * 4;
#pragma unroll
        for (int r = 0; r < 4; ++r) {
          const int m = m0 + r;
          const int b_ = m >> 12, s = m & 4095;
          const float v = acc[i][j][r] + bv;
          if (t3 == 0)
            oq[((size_t)(b_ * NH + h) * SEQ + s) * HD + d] = f2bf(v * QSCALE);
          else if (t3 == 1)
            ok[((size_t)(b_ * NH + h) * SEQ + s) * HD + d] = f2bf(v);
          else
            ov[((size_t)(b_ * NH + h) * HD + d) * SEQ + s] = f2bf(v);
        }
      }
    }
  }
}

// ---------------------------------------------------------------------------
// Causal flash attention v3 (BEST MEASURED: 88.4 us, R2): 32x32x16 MFMA,
// fully in-register P (cvt_pk + permlane32_swap), QBLK=128 / 4 waves,
// grid (24,32) stratified, LDS 32 KB.  Reverted after R3-R5 experiments
// (backfill, ILP restructure, wave-independent) all measured >= this.
// ---------------------------------------------------------------------------
typedef float f32x16 __attribute__((ext_vector_type(16)));

__device__ inline unsigned int cvtpk(float a, float b) {
  unsigned int r;
  asm("v_cvt_pk_bf16_f32 %0, %1, %2" : "=v"(r) : "v"(a), "v"(b));
  return r;
}
__device__ inline void plswap(unsigned int& x, unsigned int& y) {
  asm("v_permlane32_swap_b32 %0, %1" : "+v"(x), "+v"(y));
}

__global__ __launch_bounds__(256, 4) void flash_mfma(
    const ushort_t* __restrict__ qb, const ushort_t* __restrict__ kb,
    const ushort_t* __restrict__ vb, ushort_t* __restrict__ attn) {
  __shared__ __align__(16) ushort_t Ks[2][64 * 64];  // 16384 B
  __shared__ __align__(16) ushort_t Vt[2][64 * 64];  // 16384 B

  const int tid = threadIdx.x;
  const int w = tid >> 6;      // wave -> q sub-block (32 rows)
  const int lane = tid & 63;
  const int r32 = lane & 31;   // MFMA row index
  const int hf = lane >> 5;    // k-half (lane 0-31 vs 32-63)
  const int gk = r32 & 7;      // granule swizzle key
  const int rc4 = hf * 4;      // rowcode offset

  const int bh = blockIdx.x;   // 0..23 (fast dim, 24%8==0 -> XCD = bh%8)
  const int y = blockIdx.y;    // 0..31
  const int qt2 = (y < 11) ? (31 - y) : (y - 11);  // stratified map
  const int ktd0 = 2 * qt2;    // first diagonal k-tile
  const int nkt = 2 * qt2 + 2;

  const size_t base = (size_t)bh * SEQ * HD;
  const ushort_t* Qg = qb + base;
  const ushort_t* Kg = kb + base;
  const ushort_t* Vg = vb + base;  // [HD][SEQ]

  const int srow = lane >> 3;
  const int sg = (lane & 7) ^ srow;
  const int row0 = w * 8 + srow;
  const ushort_t* kp = Kg + (size_t)row0 * HD + (sg << 3);
  const ushort_t* vp = Vg + (size_t)row0 * SEQ + (sg << 3);

  const int qoff = w * 32 + r32;
  const int qglob = qt2 * 128 + qoff;
  bf16x8 qf[4];
  {
    const ushort_t* qrow = Qg + (size_t)qglob * HD;
#pragma unroll
    for (int dc = 0; dc < 4; ++dc)
      qf[dc] = *(const bf16x8*)(qrow + dc * 16 + hf * 8);
  }

  f32x16 oacc[2] = {};
  float lsum = 0.f;

#pragma unroll
  for (int r2 = 0; r2 < 2; ++r2) {
    __builtin_amdgcn_global_load_lds(
        (const __attribute__((address_space(1))) unsigned int*)(kp + r2 * (32 * HD)),
        (__attribute__((address_space(3))) unsigned int*)(&Ks[0][(w + r2 * 4) * 512]),
        16, 0, 0);
    __builtin_amdgcn_global_load_lds(
        (const __attribute__((address_space(1))) unsigned int*)(vp + r2 * (32 * SEQ)),
        (__attribute__((address_space(3))) unsigned int*)(&Vt[0][(w + r2 * 4) * 512]),
        16, 0, 0);
  }
  kp += 64 * HD;
  vp += 64;

  for (int kt = 0; kt < nkt; ++kt) {
    const int cur = kt & 1;
    __syncthreads();
    if (kt + 1 < nkt) {
      const int nxt = cur ^ 1;
#pragma unroll
      for (int r2 = 0; r2 < 2; ++r2) {
        __builtin_amdgcn_global_load_lds(
            (const __attribute__((address_space(1))) unsigned int*)(kp + r2 * (32 * HD)),
            (__attribute__((address_space(3))) unsigned int*)(&Ks[nxt][(w + r2 * 4) * 512]),
            16, 0, 0);
        __builtin_amdgcn_global_load_lds(
            (const __attribute__((address_space(1))) unsigned int*)(vp + r2 * (32 * SEQ)),
            (__attribute__((address_space(3))) unsigned int*)(&Vt[nxt][(w + r2 * 4) * 512]),
            16, 0, 0);
      }
      kp += 64 * HD;
      vp += 64;
    }

    const bool diag = (kt >= ktd0);
    const int kbase0 = (kt == ktd0) ? 0 : 64;

#pragma unroll
    for (int krb = 0; krb < 2; ++krb) {
      const int krow = (krb * 32 + r32) * 64;
      f32x16 s = {};
#pragma unroll
      for (int dc = 0; dc < 4; ++dc) {
        bf16x8 kf =
            *(const bf16x8*)(&Ks[cur][krow + (((2 * dc + hf) ^ gk) << 3)]);
        s = __builtin_amdgcn_mfma_f32_32x32x16_bf16(kf, qf[dc], s, 0, 0, 0);
      }
      if (diag) {
        const int kb2 = kbase0 + krb * 32;
#pragma unroll
        for (int r = 0; r < 16; ++r) {
          const int rowc = (r & 3) + 8 * (r >> 2) + rc4;
          if (kb2 + rowc > qoff) s[r] = -1e30f;
        }
      }
      float e[16];
#pragma unroll
      for (int r = 0; r < 16; ++r) {
        e[r] = EXP2F(s[r]);
        lsum += e[r];
      }
#pragma unroll
      for (int ch = 0; ch < 2; ++ch) {
        const int rb = ch * 8;
        unsigned int x0 = cvtpk(e[rb + 0], e[rb + 1]);
        unsigned int x1 = cvtpk(e[rb + 2], e[rb + 3]);
        unsigned int y0 = cvtpk(e[rb + 4], e[rb + 5]);
        unsigned int y1 = cvtpk(e[rb + 6], e[rb + 7]);
        plswap(x0, y0);
        plswap(x1, y1);
        union { unsigned int u[4]; bf16x8 v; } pf;
        pf.u[0] = x0; pf.u[1] = x1; pf.u[2] = y0; pf.u[3] = y1;
        const int c = 2 * krb + ch;
        __builtin_amdgcn_s_setprio(1);
#pragma unroll
        for (int vb2 = 0; vb2 < 2; ++vb2) {
          const int vrow = (vb2 * 32 + r32) * 64;
          bf16x8 vf =
              *(const bf16x8*)(&Vt[cur][vrow + (((2 * c + hf) ^ gk) << 3)]);
          oacc[vb2] =
              __builtin_amdgcn_mfma_f32_32x32x16_bf16(vf, pf.v, oacc[vb2], 0, 0, 0);
        }
        __builtin_amdgcn_s_setprio(0);
      }
    }
  }

  lsum += __shfl_xor(lsum, 32);
  const float inv = 1.f / lsum;
  const int b_ = bh / NH, h = bh % NH;
  ushort_t* orow = attn + (size_t)(b_ * SEQ + qglob) * EMBED + h * HD;
#pragma unroll
  for (int vb2 = 0; vb2 < 2; ++vb2)
#pragma unroll
    for (int rq = 0; rq < 4; ++rq) {
      us4 o;
#pragma unroll
      for (int r = 0; r < 4; ++r) o[r] = f2bf(oacc[vb2][rq * 4 + r] * inv);
      *(us4*)(orow + vb2 * 32 + rq * 8 + rc4) = o;
    }
}

extern "C" void kernel_launch(void* const* d_in, const int* in_sizes, int n_in,
                              void* d_out, int out_size, void* d_ws,
                              size_t ws_size, hipStream_t stream) {
  const float* x = (const float*)d_in[0];      // [B,S,E]
  const float* w_qkv = (const float*)d_in[1];  // [E,3E]
  const float* b_qkv = (const float*)d_in[2];  // [3E]
  const float* w_out = (const float*)d_in[3];  // [E,E]
  const float* b_out = (const float*)d_in[4];  // [E]
  float* out = (float*)d_out;                  // [B,S,E] fp32

  const size_t per = (size_t)BATCH * NH * SEQ * HD;  // 6291456
  ushort_t* q_buf = (ushort_t*)d_ws;          // [B,H,S,D] (scaled by QSCALE)
  ushort_t* k_buf = q_buf + per;              // [B,H,S,D]
  ushort_t* v_buf = k_buf + per;              // [B,H,D,S] (transposed)
  ushort_t* attn_buf = v_buf + per;           // [B,S,E] bf16
  ushort_t* xb = attn_buf + per;              // [M,E] bf16
  ushort_t* wqkvT = xb + per;                 // [3E,E] bf16
  ushort_t* woutT = wqkvT + (size_t)N3E * EMBED;  // [E,E] bf16

  convert_x<<<(MROWS * EMBED) / 2048, 256, 0, stream>>>(x, xb);
  transpose_w<<<dim3(N3E / 64, EMBED / 64), 256, 0, stream>>>(w_qkv, wqkvT,
                                                              EMBED, N3E);
  transpose_w<<<dim3(EMBED / 64, EMBED / 64), 256, 0, stream>>>(w_out, woutT,
                                                                EMBED, EMBED);

  dim3 g1(N3E / 256, MROWS / 256);  // (9,32)
  gemm_256<N3E, EMBED, true><<<g1, 512, 0, stream>>>(
      xb, wqkvT, b_qkv, nullptr, q_buf, k_buf, v_buf);

  dim3 g2(BATCH * NH, 32);  // bh fast (XCD = bh%8); stratified qt2 map
  flash_mfma<<<g2, 256, 0, stream>>>(q_buf, k_buf, v_buf, attn_buf);

  dim3 g3(EMBED / 256, MROWS / 256);  // (3,32)
  gemm_256<EMBED, EMBED, false><<<g3, 512, 0, stream>>>(
      attn_buf, woutT, b_out, out, nullptr, nullptr, nullptr);
}

// Round 9
// 256.850 us; speedup vs baseline: 1.1749x; 1.1042x over previous
//
#include <hip/hip_runtime.h>

#define EMBED 768
#define NH 12
#define HD 64
#define SEQ 4096
#define BATCH 2
#define MROWS (BATCH * SEQ)   // 8192
#define N3E (3 * EMBED)       // 2304

typedef short bf16x8 __attribute__((ext_vector_type(8)));  // 8 bf16 = 4 VGPRs
typedef float fx4 __attribute__((ext_vector_type(4)));     // MFMA C/D 16x16
typedef float f32x16 __attribute__((ext_vector_type(16))); // MFMA C/D 32x32
typedef unsigned short ushort_t;
typedef unsigned short us4 __attribute__((ext_vector_type(4)));  // 8B packed

#if __has_builtin(__builtin_amdgcn_exp2f)
#define EXP2F(x) __builtin_amdgcn_exp2f(x)
#else
#define EXP2F(x) exp2f(x)
#endif

// Q pre-scale: (1/sqrt(64)) * log2(e)  -> softmax runs in exp2 domain
#define QSCALE 0.18033688011112042f

// fp32 -> bf16 round-to-nearest-even
__device__ inline ushort_t f2bf(float f) {
  union { float f; unsigned int u; } x; x.f = f;
  unsigned int r = x.u + 0x7fffu + ((x.u >> 16) & 1u);
  return (ushort_t)(r >> 16);
}

// v_cvt_pk_bf16_f32 (no builtin on gfx950)
__device__ inline unsigned int cvtpk(float a, float b) {
  unsigned int r;
  asm("v_cvt_pk_bf16_f32 %0, %1, %2" : "=v"(r) : "v"(a), "v"(b));
  return r;
}
// v_permlane32_swap_b32: x[hi lanes] <-> y[lo lanes]
__device__ inline void plswap(unsigned int& x, unsigned int& y) {
  asm("v_permlane32_swap_b32 %0, %1" : "+v"(x), "+v"(y));
}

// ---------------------------------------------------------------------------
// x [M,K] fp32 -> bf16, straight copy. 8 elems/thread.
// ---------------------------------------------------------------------------
__global__ __launch_bounds__(256) void convert_x(const float* __restrict__ in,
                                                 ushort_t* __restrict__ out) {
  int i = (blockIdx.x * 256 + threadIdx.x) * 8;
  float4 a = *(const float4*)(in + i);
  float4 b = *(const float4*)(in + i + 4);
  bf16x8 o;
  o[0] = f2bf(a.x); o[1] = f2bf(a.y); o[2] = f2bf(a.z); o[3] = f2bf(a.w);
  o[4] = f2bf(b.x); o[5] = f2bf(b.y); o[6] = f2bf(b.z); o[7] = f2bf(b.w);
  *(bf16x8*)(out + i) = o;
}

// ---------------------------------------------------------------------------
// W [K,N] fp32 -> W^T [N,K] bf16 via 64x64 LDS tile (stride 65: conflict-free)
// ---------------------------------------------------------------------------
__global__ __launch_bounds__(256) void transpose_w(const float* __restrict__ in,
                                                   ushort_t* __restrict__ out,
                                                   int K, int N) {
  __shared__ float t[64][65];
  const int bn = blockIdx.x * 64, bk = blockIdx.y * 64;
  const int c = threadIdx.x & 63, r0 = threadIdx.x >> 6;
#pragma unroll
  for (int rr = 0; rr < 16; ++rr) {
    int row = rr * 4 + r0;
    t[row][c] = in[(size_t)(bk + row) * N + bn + c];
  }
  __syncthreads();
#pragma unroll
  for (int rr = 0; rr < 16; ++rr) {
    int row = rr * 4 + r0;
    out[(size_t)(bn + row) * K + bk + c] = f2bf(t[c][row]);
  }
}

// ---------------------------------------------------------------------------
// bf16 MFMA GEMM v3b: m97 128x128 geometry + {triple-buffer LDS, stage-2-ahead
// counted vmcnt(4), ONE barrier/K-step, bijective XCD swizzle} +
// sched_barrier(0) fences (R8: close the barrier/ds_read code-motion race --
// s_barrier doesn't model memory, so a COMPUTE ds_read could be scheduled
// between the vmcnt asm and the barrier, reading another wave's un-landed
// DMA chunk.  sched_barrier(0) pins: vmcnt -> barrier -> fence -> STAGE ->
// COMPUTE).
//  * Buffers cycle t%3.  Per step t: [vmcnt(4) (tile t landed; t+1 in
//    flight) ; s_barrier ; STAGE(t+2 -> (t-1)%3) ; ds_read+16 MFMA on t%3].
//    Last tile peeled with vmcnt(0) (R6 tail-race fix).
//  * Issue-order audit: per wave, all 4 loads of tile k issue in step k-2,
//    strictly before any load of tile k+1 (asm memory clobbers pin stage
//    issues between consecutive vmcnt waits) -> vmcnt(4) == "tile t landed".
//  * WAR audit: STAGE(t+2) targets buf (t-1)%3; every wave's iter-(t-1)
//    ds_reads completed (lgkm-waited before their MFMAs) before it reached
//    the iter-t barrier -> no overwrite-before-read.
//  * LDS 48 KB -> 3 blocks/CU (12 waves) for inter-block latency hiding.
//  * XCD swizzle: lin' = (lin%8)*(nwg/8) + lin/8 (nwg%8==0 for both grids).
// SCATTER epilogue identical to v1 (q scaled / k / v-transposed bf16).
// ---------------------------------------------------------------------------
template <int N_, int K_, bool SCATTER>
__global__ __launch_bounds__(256) void gemm_mfma(
    const ushort_t* __restrict__ A, const ushort_t* __restrict__ Bt,
    const float* __restrict__ bias, float* __restrict__ outF,
    ushort_t* __restrict__ oq, ushort_t* __restrict__ ok,
    ushort_t* __restrict__ ov) {
  constexpr int NT = K_ / 32;  // 24
  __shared__ __align__(16) ushort_t As[3][128 * 32];  // 24 KB
  __shared__ __align__(16) ushort_t Bs[3][128 * 32];  // 24 KB
  const int tid = threadIdx.x;
  const int w = tid >> 6, lane = tid & 63;
  const int quad = lane >> 4, ln = lane & 15;

  // ---- bijective XCD swizzle (nwg % 8 == 0 for both grids) ----
  const int gx = gridDim.x;
  const int nwg = gx * gridDim.y;
  int lin = blockIdx.y * gx + blockIdx.x;
  lin = (lin & 7) * (nwg >> 3) + (lin >> 3);
  const int bm = (lin / gx) * 128, bn = (lin % gx) * 128;

  const int wm = (w >> 1) * 64, wn = (w & 1) * 64;
  const int sr = lane >> 2;     // row within 16-row chunk
  const int sslot = lane & 3;   // 16B slot within row

  auto STAGE = [&](int ti, int b) {
#pragma unroll
    for (int r = 0; r < 2; ++r) {
      const int c = w + r * 4;        // chunk 0..7 (wave-uniform)
      const int m = c * 16 + sr;      // tile row 0..127
      const int kk = ti * 32 + ((sslot ^ (m & 3)) << 3);
      __builtin_amdgcn_global_load_lds(
          (const __attribute__((address_space(1))) unsigned int*)
              (A + (size_t)(bm + m) * K_ + kk),
          (__attribute__((address_space(3))) unsigned int*)(&As[b][c * 512]),
          16, 0, 0);
      __builtin_amdgcn_global_load_lds(
          (const __attribute__((address_space(1))) unsigned int*)
              (Bt + (size_t)(bn + m) * K_ + kk),
          (__attribute__((address_space(3))) unsigned int*)(&Bs[b][c * 512]),
          16, 0, 0);
    }
  };

  fx4 acc[4][4] = {};

  auto COMPUTE = [&](int b) {
    bf16x8 af[4], bfr[4];
#pragma unroll
    for (int i = 0; i < 4; ++i) {
      const int m = wm + i * 16 + ln;
      af[i] = *(const bf16x8*)(&As[b][m * 32 + ((quad ^ (m & 3)) << 3)]);
    }
#pragma unroll
    for (int j = 0; j < 4; ++j) {
      const int n = wn + j * 16 + ln;
      bfr[j] = *(const bf16x8*)(&Bs[b][n * 32 + ((quad ^ (n & 3)) << 3)]);
    }
#pragma unroll
    for (int i = 0; i < 4; ++i)
#pragma unroll
      for (int j = 0; j < 4; ++j)
        acc[i][j] = __builtin_amdgcn_mfma_f32_16x16x32_bf16(af[i], bfr[j],
                                                            acc[i][j], 0, 0, 0);
  };

  // ---- prologue: stage tiles 0,1 ----
  STAGE(0, 0);
  STAGE(1, 1);

  int bufR = 0;
  for (int t = 0; t < NT - 2; ++t) {
    asm volatile("s_waitcnt vmcnt(4)" ::: "memory");  // tile t landed (this wave)
    __builtin_amdgcn_s_barrier();                      // cross-wave publish
    __builtin_amdgcn_sched_barrier(0);                 // no motion across
    const int bufS = (bufR >= 1) ? bufR - 1 : 2;       // (t+2)%3 == (t-1)%3
    STAGE(t + 2, bufS);
    COMPUTE(bufR);
    bufR = (bufR < 2) ? bufR + 1 : 0;
  }
  // t = NT-2: tiles NT-2, NT-1 outstanding -> vmcnt(4) waits for NT-2
  asm volatile("s_waitcnt vmcnt(4)" ::: "memory");
  __builtin_amdgcn_s_barrier();
  __builtin_amdgcn_sched_barrier(0);
  COMPUTE(bufR);
  bufR = (bufR < 2) ? bufR + 1 : 0;
  // t = NT-1: only 4 outstanding -> must drain fully (R6 race fix)
  asm volatile("s_waitcnt vmcnt(0)" ::: "memory");
  __builtin_amdgcn_s_barrier();
  __builtin_amdgcn_sched_barrier(0);
  COMPUTE(bufR);

  // ---- epilogue ----
  if (!SCATTER) {
#pragma unroll
    for (int j = 0; j < 4; ++j) {
      const int n = bn + wn + j * 16 + ln;
      const float bv = bias[n];
#pragma unroll
      for (int i = 0; i < 4; ++i) {
        const int m0 = bm + wm + i * 16 + quad * 4;
#pragma unroll
        for (int r = 0; r < 4; ++r)
          outF[(size_t)(m0 + r) * N_ + n] = acc[i][j][r] + bv;
      }
    }
  } else {
    const int t3 = bn / EMBED;  // 768 % 128 == 0: whole tile in one of q/k/v
#pragma unroll
    for (int j = 0; j < 4; ++j) {
      const int nn = bn + wn + j * 16 + ln;
      const int rem = nn - t3 * EMBED;
      const int h = rem >> 6, d = rem & 63;
      const float bv = bias[nn];
#pragma unroll
      for (int i = 0; i < 4; ++i) {
        const int m0 = bm + wm + i * 16 + quad * 4;
#pragma unroll
        for (int r = 0; r < 4; ++r) {
          const int m = m0 + r;
          const int b_ = m >> 12, s = m & 4095;
          const float v = acc[i][j][r] + bv;
          if (t3 == 0)
            oq[((size_t)(b_ * NH + h) * SEQ + s) * HD + d] = f2bf(v * QSCALE);
          else if (t3 == 1)
            ok[((size_t)(b_ * NH + h) * SEQ + s) * HD + d] = f2bf(v);
          else
            ov[((size_t)(b_ * NH + h) * HD + d) * SEQ + s] = f2bf(v);
        }
      }
    }
  }
}

// ---------------------------------------------------------------------------
// Causal flash attention v3 (BEST MEASURED: 88.4 us, R2): 32x32x16 MFMA,
// fully in-register P (cvt_pk + permlane32_swap), QBLK=128 / 4 waves,
// grid (24,32) stratified, LDS 32 KB.  R3-R5 alternatives all measured >=.
// ---------------------------------------------------------------------------
__global__ __launch_bounds__(256, 4) void flash_mfma(
    const ushort_t* __restrict__ qb, const ushort_t* __restrict__ kb,
    const ushort_t* __restrict__ vb, ushort_t* __restrict__ attn) {
  __shared__ __align__(16) ushort_t Ks[2][64 * 64];  // 16384 B
  __shared__ __align__(16) ushort_t Vt[2][64 * 64];  // 16384 B

  const int tid = threadIdx.x;
  const int w = tid >> 6;      // wave -> q sub-block (32 rows)
  const int lane = tid & 63;
  const int r32 = lane & 31;   // MFMA row index
  const int hf = lane >> 5;    // k-half (lane 0-31 vs 32-63)
  const int gk = r32 & 7;      // granule swizzle key
  const int rc4 = hf * 4;      // rowcode offset

  const int bh = blockIdx.x;   // 0..23 (fast dim, 24%8==0 -> XCD = bh%8)
  const int y = blockIdx.y;    // 0..31
  const int qt2 = (y < 11) ? (31 - y) : (y - 11);  // stratified map
  const int ktd0 = 2 * qt2;    // first diagonal k-tile
  const int nkt = 2 * qt2 + 2;

  const size_t base = (size_t)bh * SEQ * HD;
  const ushort_t* Qg = qb + base;
  const ushort_t* Kg = kb + base;
  const ushort_t* Vg = vb + base;  // [HD][SEQ]

  const int srow = lane >> 3;
  const int sg = (lane & 7) ^ srow;
  const int row0 = w * 8 + srow;
  const ushort_t* kp = Kg + (size_t)row0 * HD + (sg << 3);
  const ushort_t* vp = Vg + (size_t)row0 * SEQ + (sg << 3);

  const int qoff = w * 32 + r32;
  const int qglob = qt2 * 128 + qoff;
  bf16x8 qf[4];
  {
    const ushort_t* qrow = Qg + (size_t)qglob * HD;
#pragma unroll
    for (int dc = 0; dc < 4; ++dc)
      qf[dc] = *(const bf16x8*)(qrow + dc * 16 + hf * 8);
  }

  f32x16 oacc[2] = {};
  float lsum = 0.f;

#pragma unroll
  for (int r2 = 0; r2 < 2; ++r2) {
    __builtin_amdgcn_global_load_lds(
        (const __attribute__((address_space(1))) unsigned int*)(kp + r2 * (32 * HD)),
        (__attribute__((address_space(3))) unsigned int*)(&Ks[0][(w + r2 * 4) * 512]),
        16, 0, 0);
    __builtin_amdgcn_global_load_lds(
        (const __attribute__((address_space(1))) unsigned int*)(vp + r2 * (32 * SEQ)),
        (__attribute__((address_space(3))) unsigned int*)(&Vt[0][(w + r2 * 4) * 512]),
        16, 0, 0);
  }
  kp += 64 * HD;
  vp += 64;

  for (int kt = 0; kt < nkt; ++kt) {
    const int cur = kt & 1;
    __syncthreads();
    if (kt + 1 < nkt) {
      const int nxt = cur ^ 1;
#pragma unroll
      for (int r2 = 0; r2 < 2; ++r2) {
        __builtin_amdgcn_global_load_lds(
            (const __attribute__((address_space(1))) unsigned int*)(kp + r2 * (32 * HD)),
            (__attribute__((address_space(3))) unsigned int*)(&Ks[nxt][(w + r2 * 4) * 512]),
            16, 0, 0);
        __builtin_amdgcn_global_load_lds(
            (const __attribute__((address_space(1))) unsigned int*)(vp + r2 * (32 * SEQ)),
            (__attribute__((address_space(3))) unsigned int*)(&Vt[nxt][(w + r2 * 4) * 512]),
            16, 0, 0);
      }
      kp += 64 * HD;
      vp += 64;
    }

    const bool diag = (kt >= ktd0);
    const int kbase0 = (kt == ktd0) ? 0 : 64;

#pragma unroll
    for (int krb = 0; krb < 2; ++krb) {
      const int krow = (krb * 32 + r32) * 64;
      f32x16 s = {};
#pragma unroll
      for (int dc = 0; dc < 4; ++dc) {
        bf16x8 kf =
            *(const bf16x8*)(&Ks[cur][krow + (((2 * dc + hf) ^ gk) << 3)]);
        s = __builtin_amdgcn_mfma_f32_32x32x16_bf16(kf, qf[dc], s, 0, 0, 0);
      }
      if (diag) {
        const int kb2 = kbase0 + krb * 32;
#pragma unroll
        for (int r = 0; r < 16; ++r) {
          const int rowc = (r & 3) + 8 * (r >> 2) + rc4;
          if (kb2 + rowc > qoff) s[r] = -1e30f;
        }
      }
      float e[16];
#pragma unroll
      for (int r = 0; r < 16; ++r) {
        e[r] = EXP2F(s[r]);
        lsum += e[r];
      }
#pragma unroll
      for (int ch = 0; ch < 2; ++ch) {
        const int rb = ch * 8;
        unsigned int x0 = cvtpk(e[rb + 0], e[rb + 1]);
        unsigned int x1 = cvtpk(e[rb + 2], e[rb + 3]);
        unsigned int y0 = cvtpk(e[rb + 4], e[rb + 5]);
        unsigned int y1 = cvtpk(e[rb + 6], e[rb + 7]);
        plswap(x0, y0);
        plswap(x1, y1);
        union { unsigned int u[4]; bf16x8 v; } pf;
        pf.u[0] = x0; pf.u[1] = x1; pf.u[2] = y0; pf.u[3] = y1;
        const int c = 2 * krb + ch;
        __builtin_amdgcn_s_setprio(1);
#pragma unroll
        for (int vb2 = 0; vb2 < 2; ++vb2) {
          const int vrow = (vb2 * 32 + r32) * 64;
          bf16x8 vf =
              *(const bf16x8*)(&Vt[cur][vrow + (((2 * c + hf) ^ gk) << 3)]);
          oacc[vb2] =
              __builtin_amdgcn_mfma_f32_32x32x16_bf16(vf, pf.v, oacc[vb2], 0, 0, 0);
        }
        __builtin_amdgcn_s_setprio(0);
      }
    }
  }

  lsum += __shfl_xor(lsum, 32);
  const float inv = 1.f / lsum;
  const int b_ = bh / NH, h = bh % NH;
  ushort_t* orow = attn + (size_t)(b_ * SEQ + qglob) * EMBED + h * HD;
#pragma unroll
  for (int vb2 = 0; vb2 < 2; ++vb2)
#pragma unroll
    for (int rq = 0; rq < 4; ++rq) {
      us4 o;
#pragma unroll
      for (int r = 0; r < 4; ++r) o[r] = f2bf(oacc[vb2][rq * 4 + r] * inv);
      *(us4*)(orow + vb2 * 32 + rq * 8 + rc4) = o;
    }
}

extern "C" void kernel_launch(void* const* d_in, const int* in_sizes, int n_in,
                              void* d_out, int out_size, void* d_ws,
                              size_t ws_size, hipStream_t stream) {
  const float* x = (const float*)d_in[0];      // [B,S,E]
  const float* w_qkv = (const float*)d_in[1];  // [E,3E]
  const float* b_qkv = (const float*)d_in[2];  // [3E]
  const float* w_out = (const float*)d_in[3];  // [E,E]
  const float* b_out = (const float*)d_in[4];  // [E]
  float* out = (float*)d_out;                  // [B,S,E] fp32

  const size_t per = (size_t)BATCH * NH * SEQ * HD;  // 6291456
  ushort_t* q_buf = (ushort_t*)d_ws;          // [B,H,S,D] (scaled by QSCALE)
  ushort_t* k_buf = q_buf + per;              // [B,H,S,D]
  ushort_t* v_buf = k_buf + per;              // [B,H,D,S] (transposed)
  ushort_t* attn_buf = v_buf + per;           // [B,S,E] bf16
  ushort_t* xb = attn_buf + per;              // [M,E] bf16
  ushort_t* wqkvT = xb + per;                 // [3E,E] bf16
  ushort_t* woutT = wqkvT + (size_t)N3E * EMBED;  // [E,E] bf16

  convert_x<<<(MROWS * EMBED) / 2048, 256, 0, stream>>>(x, xb);
  transpose_w<<<dim3(N3E / 64, EMBED / 64), 256, 0, stream>>>(w_qkv, wqkvT,
                                                              EMBED, N3E);
  transpose_w<<<dim3(EMBED / 64, EMBED / 64), 256, 0, stream>>>(w_out, woutT,
                                                                EMBED, EMBED);

  dim3 g1(N3E / 128, MROWS / 128);  // (18,64) = 1152 blocks
  gemm_mfma<N3E, EMBED, true><<<g1, 256, 0, stream>>>(
      xb, wqkvT, b_qkv, nullptr, q_buf, k_buf, v_buf);

  dim3 g2(BATCH * NH, 32);  // bh fast (XCD = bh%8); stratified qt2 map
  flash_mfma<<<g2, 256, 0, stream>>>(q_buf, k_buf, v_buf, attn_buf);

  dim3 g3(EMBED / 128, MROWS / 128);  // (6,64) = 384 blocks
  gemm_mfma<EMBED, EMBED, false><<<g3, 256, 0, stream>>>(
      attn_buf, woutT, b_out, out, nullptr, nullptr, nullptr);
}

// Round 10
// 229.332 us; speedup vs baseline: 1.3159x; 1.1200x over previous
//
#include <hip/hip_runtime.h>

#define EMBED 768
#define NH 12
#define HD 64
#define SEQ 4096
#define BATCH 2
#define MROWS (BATCH * SEQ)   // 8192
#define N3E (3 * EMBED)       // 2304

typedef short bf16x8 __attribute__((ext_vector_type(8)));  // 8 bf16 = 4 VGPRs
typedef float fx4 __attribute__((ext_vector_type(4)));     // MFMA C/D 16x16
typedef float f32x16 __attribute__((ext_vector_type(16))); // MFMA C/D 32x32
typedef unsigned short ushort_t;
typedef unsigned short us4 __attribute__((ext_vector_type(4)));  // 8B packed

#if __has_builtin(__builtin_amdgcn_exp2f)
#define EXP2F(x) __builtin_amdgcn_exp2f(x)
#else
#define EXP2F(x) exp2f(x)
#endif

// Q pre-scale: (1/sqrt(64)) * log2(e)  -> softmax runs in exp2 domain
#define QSCALE 0.18033688011112042f

// fp32 -> bf16 round-to-nearest-even
__device__ inline ushort_t f2bf(float f) {
  union { float f; unsigned int u; } x; x.f = f;
  unsigned int r = x.u + 0x7fffu + ((x.u >> 16) & 1u);
  return (ushort_t)(r >> 16);
}

// v_cvt_pk_bf16_f32 (no builtin on gfx950)
__device__ inline unsigned int cvtpk(float a, float b) {
  unsigned int r;
  asm("v_cvt_pk_bf16_f32 %0, %1, %2" : "=v"(r) : "v"(a), "v"(b));
  return r;
}
// v_permlane32_swap_b32: x[hi lanes] <-> y[lo lanes]
__device__ inline void plswap(unsigned int& x, unsigned int& y) {
  asm("v_permlane32_swap_b32 %0, %1" : "+v"(x), "+v"(y));
}

// ---------------------------------------------------------------------------
// x [M,K] fp32 -> bf16, straight copy. 8 elems/thread.
// ---------------------------------------------------------------------------
__global__ __launch_bounds__(256) void convert_x(const float* __restrict__ in,
                                                 ushort_t* __restrict__ out) {
  int i = (blockIdx.x * 256 + threadIdx.x) * 8;
  float4 a = *(const float4*)(in + i);
  float4 b = *(const float4*)(in + i + 4);
  bf16x8 o;
  o[0] = f2bf(a.x); o[1] = f2bf(a.y); o[2] = f2bf(a.z); o[3] = f2bf(a.w);
  o[4] = f2bf(b.x); o[5] = f2bf(b.y); o[6] = f2bf(b.z); o[7] = f2bf(b.w);
  *(bf16x8*)(out + i) = o;
}

// ---------------------------------------------------------------------------
// W [K,N] fp32 -> W^T [N,K] bf16 via 64x64 LDS tile (stride 65: conflict-free)
// ---------------------------------------------------------------------------
__global__ __launch_bounds__(256) void transpose_w(const float* __restrict__ in,
                                                   ushort_t* __restrict__ out,
                                                   int K, int N) {
  __shared__ float t[64][65];
  const int bn = blockIdx.x * 64, bk = blockIdx.y * 64;
  const int c = threadIdx.x & 63, r0 = threadIdx.x >> 6;
#pragma unroll
  for (int rr = 0; rr < 16; ++rr) {
    int row = rr * 4 + r0;
    t[row][c] = in[(size_t)(bk + row) * N + bn + c];
  }
  __syncthreads();
#pragma unroll
  for (int rr = 0; rr < 16; ++rr) {
    int row = rr * 4 + r0;
    out[(size_t)(bn + row) * K + bk + c] = f2bf(t[c][row]);
  }
}

// ---------------------------------------------------------------------------
// bf16 MFMA GEMM v4: v3b K-loop (m97 128x128, triple-buffer, counted vmcnt(4),
// one barrier/K-step, XCD swizzle, sched_barrier fences) + NEW V-EPILOGUE:
//  * R9 post-mortem: gemm1+gemm2 ~ 150 us at ~260 TF effective while the
//    K-loop matches m97 (v3b == v1 within noise) -> epilogue-bound.
//    R6 evidence: gemm1 WRITE_SIZE 63.9 MB vs 37.7 ideal (1.7x write
//    amplification).  The V scatter writes 2B elements 8 KB apart per lane
//    (64 scattered wave-stores/thread, partial-line HBM writebacks).
//  * Fix (t3==2 blocks only): transpose through LDS (staging buffers are
//    dead after the K-loop): acc -> smem[n][m ^ ((n&7)<<4)] bf16 (XOR keeps
//    stores <=4-way banked), barrier, then stream bf16x8 chunks: each wave
//    writes 4 x 256B contiguous [B,H,D,S] segments per instruction.
//  * Audit: __syncthreads() before LDS reuse (K-loop ds_reads drained by
//    barrier semantics); branch is block-uniform (bn per block); XOR key is
//    a multiple of 16 so 8-elem chunks stay contiguous; bm 128-aligned ->
//    single batch per block.
// ---------------------------------------------------------------------------
template <int N_, int K_, bool SCATTER>
__global__ __launch_bounds__(256) void gemm_mfma(
    const ushort_t* __restrict__ A, const ushort_t* __restrict__ Bt,
    const float* __restrict__ bias, float* __restrict__ outF,
    ushort_t* __restrict__ oq, ushort_t* __restrict__ ok,
    ushort_t* __restrict__ ov) {
  constexpr int NT = K_ / 32;  // 24
  __shared__ __align__(16) ushort_t smem[24576];  // 48 KB: As[3]|Bs[3], reused
  ushort_t* As_ = smem;            // [3][128*32]
  ushort_t* Bs_ = smem + 12288;    // [3][128*32]
  const int tid = threadIdx.x;
  const int w = tid >> 6, lane = tid & 63;
  const int quad = lane >> 4, ln = lane & 15;

  // ---- bijective XCD swizzle (nwg % 8 == 0 for both grids) ----
  const int gx = gridDim.x;
  const int nwg = gx * gridDim.y;
  int lin = blockIdx.y * gx + blockIdx.x;
  lin = (lin & 7) * (nwg >> 3) + (lin >> 3);
  const int bm = (lin / gx) * 128, bn = (lin % gx) * 128;

  const int wm = (w >> 1) * 64, wn = (w & 1) * 64;
  const int sr = lane >> 2;     // row within 16-row chunk
  const int sslot = lane & 3;   // 16B slot within row

  auto STAGE = [&](int ti, int b) {
#pragma unroll
    for (int r = 0; r < 2; ++r) {
      const int c = w + r * 4;        // chunk 0..7 (wave-uniform)
      const int m = c * 16 + sr;      // tile row 0..127
      const int kk = ti * 32 + ((sslot ^ (m & 3)) << 3);
      __builtin_amdgcn_global_load_lds(
          (const __attribute__((address_space(1))) unsigned int*)
              (A + (size_t)(bm + m) * K_ + kk),
          (__attribute__((address_space(3))) unsigned int*)(As_ + b * 4096 + c * 512),
          16, 0, 0);
      __builtin_amdgcn_global_load_lds(
          (const __attribute__((address_space(1))) unsigned int*)
              (Bt + (size_t)(bn + m) * K_ + kk),
          (__attribute__((address_space(3))) unsigned int*)(Bs_ + b * 4096 + c * 512),
          16, 0, 0);
    }
  };

  fx4 acc[4][4] = {};

  auto COMPUTE = [&](int b) {
    bf16x8 af[4], bfr[4];
#pragma unroll
    for (int i = 0; i < 4; ++i) {
      const int m = wm + i * 16 + ln;
      af[i] = *(const bf16x8*)(As_ + b * 4096 + m * 32 + ((quad ^ (m & 3)) << 3));
    }
#pragma unroll
    for (int j = 0; j < 4; ++j) {
      const int n = wn + j * 16 + ln;
      bfr[j] = *(const bf16x8*)(Bs_ + b * 4096 + n * 32 + ((quad ^ (n & 3)) << 3));
    }
#pragma unroll
    for (int i = 0; i < 4; ++i)
#pragma unroll
      for (int j = 0; j < 4; ++j)
        acc[i][j] = __builtin_amdgcn_mfma_f32_16x16x32_bf16(af[i], bfr[j],
                                                            acc[i][j], 0, 0, 0);
  };

  // ---- prologue: stage tiles 0,1 ----
  STAGE(0, 0);
  STAGE(1, 1);

  int bufR = 0;
  for (int t = 0; t < NT - 2; ++t) {
    asm volatile("s_waitcnt vmcnt(4)" ::: "memory");  // tile t landed (this wave)
    __builtin_amdgcn_s_barrier();                      // cross-wave publish
    __builtin_amdgcn_sched_barrier(0);                 // no motion across
    const int bufS = (bufR >= 1) ? bufR - 1 : 2;       // (t+2)%3 == (t-1)%3
    STAGE(t + 2, bufS);
    COMPUTE(bufR);
    bufR = (bufR < 2) ? bufR + 1 : 0;
  }
  // t = NT-2: tiles NT-2, NT-1 outstanding -> vmcnt(4) waits for NT-2
  asm volatile("s_waitcnt vmcnt(4)" ::: "memory");
  __builtin_amdgcn_s_barrier();
  __builtin_amdgcn_sched_barrier(0);
  COMPUTE(bufR);
  bufR = (bufR < 2) ? bufR + 1 : 0;
  // t = NT-1: only 4 outstanding -> must drain fully
  asm volatile("s_waitcnt vmcnt(0)" ::: "memory");
  __builtin_amdgcn_s_barrier();
  __builtin_amdgcn_sched_barrier(0);
  COMPUTE(bufR);

  // ---- epilogue ----
  if (!SCATTER) {
#pragma unroll
    for (int j = 0; j < 4; ++j) {
      const int n = bn + wn + j * 16 + ln;
      const float bv = bias[n];
#pragma unroll
      for (int i = 0; i < 4; ++i) {
        const int m0 = bm + wm + i * 16 + quad * 4;
#pragma unroll
        for (int r = 0; r < 4; ++r)
          outF[(size_t)(m0 + r) * N_ + n] = acc[i][j][r] + bv;
      }
    }
  } else {
    const int t3 = bn / EMBED;  // 768 % 128 == 0: whole tile in one of q/k/v
    if (t3 == 2) {
      // ---- V: LDS-transpose -> coalesced [B,H,D,S] bf16x8 writes ----
      __syncthreads();  // all waves' K-loop LDS reads complete
#pragma unroll
      for (int j = 0; j < 4; ++j) {
        const int nl = wn + j * 16 + ln;        // local n (0..127)
        const float bv = bias[bn + nl];
        const int key = (nl & 7) << 4;          // XOR bank-spread (x16 elems)
#pragma unroll
        for (int i = 0; i < 4; ++i) {
          const int m0 = wm + i * 16 + quad * 4;
#pragma unroll
          for (int r = 0; r < 4; ++r)
            smem[nl * 128 + ((m0 + r) ^ key)] = f2bf(acc[i][j][r] + bv);
        }
      }
      __syncthreads();
      const int b_ = bm >> 12, s0 = bm & 4095;
      const int lr = lane >> 4;   // row-within-group (0..3)
      const int lc = lane & 15;   // 16B chunk within 256B row
#pragma unroll
      for (int it = 0; it < 8; ++it) {
        const int nl = w * 32 + it * 4 + lr;    // local n (0..127)
        const int rem = bn + nl - 2 * EMBED;
        const int h = rem >> 6, d = rem & 63;
        const int mc = lc * 8;                  // logical m chunk (8 elems)
        bf16x8 val =
            *(const bf16x8*)&smem[nl * 128 + (mc ^ ((nl & 7) << 4))];
        *(bf16x8*)&ov[((size_t)(b_ * NH + h) * HD + d) * SEQ + s0 + mc] = val;
      }
    } else {
      // ---- Q/K: direct stores (32B/quad segments, line-combined in L2) ----
#pragma unroll
      for (int j = 0; j < 4; ++j) {
        const int nn = bn + wn + j * 16 + ln;
        const int rem = nn - t3 * EMBED;
        const int h = rem >> 6, d = rem & 63;
        const float bv = bias[nn];
#pragma unroll
        for (int i = 0; i < 4; ++i) {
          const int m0 = bm + wm + i * 16 + quad * 4;
#pragma unroll
          for (int r = 0; r < 4; ++r) {
            const int m = m0 + r;
            const int b_ = m >> 12, s = m & 4095;
            const float v = acc[i][j][r] + bv;
            if (t3 == 0)
              oq[((size_t)(b_ * NH + h) * SEQ + s) * HD + d] = f2bf(v * QSCALE);
            else
              ok[((size_t)(b_ * NH + h) * SEQ + s) * HD + d] = f2bf(v);
          }
        }
      }
    }
  }
}

// ---------------------------------------------------------------------------
// Causal flash attention v3 (BEST MEASURED: 88.4 us, R2): 32x32x16 MFMA,
// fully in-register P (cvt_pk + permlane32_swap), QBLK=128 / 4 waves,
// grid (24,32) stratified, LDS 32 KB.  R3-R5 alternatives all measured >=.
// ---------------------------------------------------------------------------
__global__ __launch_bounds__(256, 4) void flash_mfma(
    const ushort_t* __restrict__ qb, const ushort_t* __restrict__ kb,
    const ushort_t* __restrict__ vb, ushort_t* __restrict__ attn) {
  __shared__ __align__(16) ushort_t Ks[2][64 * 64];  // 16384 B
  __shared__ __align__(16) ushort_t Vt[2][64 * 64];  // 16384 B

  const int tid = threadIdx.x;
  const int w = tid >> 6;      // wave -> q sub-block (32 rows)
  const int lane = tid & 63;
  const int r32 = lane & 31;   // MFMA row index
  const int hf = lane >> 5;    // k-half (lane 0-31 vs 32-63)
  const int gk = r32 & 7;      // granule swizzle key
  const int rc4 = hf * 4;      // rowcode offset

  const int bh = blockIdx.x;   // 0..23 (fast dim, 24%8==0 -> XCD = bh%8)
  const int y = blockIdx.y;    // 0..31
  const int qt2 = (y < 11) ? (31 - y) : (y - 11);  // stratified map
  const int ktd0 = 2 * qt2;    // first diagonal k-tile
  const int nkt = 2 * qt2 + 2;

  const size_t base = (size_t)bh * SEQ * HD;
  const ushort_t* Qg = qb + base;
  const ushort_t* Kg = kb + base;
  const ushort_t* Vg = vb + base;  // [HD][SEQ]

  const int srow = lane >> 3;
  const int sg = (lane & 7) ^ srow;
  const int row0 = w * 8 + srow;
  const ushort_t* kp = Kg + (size_t)row0 * HD + (sg << 3);
  const ushort_t* vp = Vg + (size_t)row0 * SEQ + (sg << 3);

  const int qoff = w * 32 + r32;
  const int qglob = qt2 * 128 + qoff;
  bf16x8 qf[4];
  {
    const ushort_t* qrow = Qg + (size_t)qglob * HD;
#pragma unroll
    for (int dc = 0; dc < 4; ++dc)
      qf[dc] = *(const bf16x8*)(qrow + dc * 16 + hf * 8);
  }

  f32x16 oacc[2] = {};
  float lsum = 0.f;

#pragma unroll
  for (int r2 = 0; r2 < 2; ++r2) {
    __builtin_amdgcn_global_load_lds(
        (const __attribute__((address_space(1))) unsigned int*)(kp + r2 * (32 * HD)),
        (__attribute__((address_space(3))) unsigned int*)(&Ks[0][(w + r2 * 4) * 512]),
        16, 0, 0);
    __builtin_amdgcn_global_load_lds(
        (const __attribute__((address_space(1))) unsigned int*)(vp + r2 * (32 * SEQ)),
        (__attribute__((address_space(3))) unsigned int*)(&Vt[0][(w + r2 * 4) * 512]),
        16, 0, 0);
  }
  kp += 64 * HD;
  vp += 64;

  for (int kt = 0; kt < nkt; ++kt) {
    const int cur = kt & 1;
    __syncthreads();
    if (kt + 1 < nkt) {
      const int nxt = cur ^ 1;
#pragma unroll
      for (int r2 = 0; r2 < 2; ++r2) {
        __builtin_amdgcn_global_load_lds(
            (const __attribute__((address_space(1))) unsigned int*)(kp + r2 * (32 * HD)),
            (__attribute__((address_space(3))) unsigned int*)(&Ks[nxt][(w + r2 * 4) * 512]),
            16, 0, 0);
        __builtin_amdgcn_global_load_lds(
            (const __attribute__((address_space(1))) unsigned int*)(vp + r2 * (32 * SEQ)),
            (__attribute__((address_space(3))) unsigned int*)(&Vt[nxt][(w + r2 * 4) * 512]),
            16, 0, 0);
      }
      kp += 64 * HD;
      vp += 64;
    }

    const bool diag = (kt >= ktd0);
    const int kbase0 = (kt == ktd0) ? 0 : 64;

#pragma unroll
    for (int krb = 0; krb < 2; ++krb) {
      const int krow = (krb * 32 + r32) * 64;
      f32x16 s = {};
#pragma unroll
      for (int dc = 0; dc < 4; ++dc) {
        bf16x8 kf =
            *(const bf16x8*)(&Ks[cur][krow + (((2 * dc + hf) ^ gk) << 3)]);
        s = __builtin_amdgcn_mfma_f32_32x32x16_bf16(kf, qf[dc], s, 0, 0, 0);
      }
      if (diag) {
        const int kb2 = kbase0 + krb * 32;
#pragma unroll
        for (int r = 0; r < 16; ++r) {
          const int rowc = (r & 3) + 8 * (r >> 2) + rc4;
          if (kb2 + rowc > qoff) s[r] = -1e30f;
        }
      }
      float e[16];
#pragma unroll
      for (int r = 0; r < 16; ++r) {
        e[r] = EXP2F(s[r]);
        lsum += e[r];
      }
#pragma unroll
      for (int ch = 0; ch < 2; ++ch) {
        const int rb = ch * 8;
        unsigned int x0 = cvtpk(e[rb + 0], e[rb + 1]);
        unsigned int x1 = cvtpk(e[rb + 2], e[rb + 3]);
        unsigned int y0 = cvtpk(e[rb + 4], e[rb + 5]);
        unsigned int y1 = cvtpk(e[rb + 6], e[rb + 7]);
        plswap(x0, y0);
        plswap(x1, y1);
        union { unsigned int u[4]; bf16x8 v; } pf;
        pf.u[0] = x0; pf.u[1] = x1; pf.u[2] = y0; pf.u[3] = y1;
        const int c = 2 * krb + ch;
        __builtin_amdgcn_s_setprio(1);
#pragma unroll
        for (int vb2 = 0; vb2 < 2; ++vb2) {
          const int vrow = (vb2 * 32 + r32) * 64;
          bf16x8 vf =
              *(const bf16x8*)(&Vt[cur][vrow + (((2 * c + hf) ^ gk) << 3)]);
          oacc[vb2] =
              __builtin_amdgcn_mfma_f32_32x32x16_bf16(vf, pf.v, oacc[vb2], 0, 0, 0);
        }
        __builtin_amdgcn_s_setprio(0);
      }
    }
  }

  lsum += __shfl_xor(lsum, 32);
  const float inv = 1.f / lsum;
  const int b_ = bh / NH, h = bh % NH;
  ushort_t* orow = attn + (size_t)(b_ * SEQ + qglob) * EMBED + h * HD;
#pragma unroll
  for (int vb2 = 0; vb2 < 2; ++vb2)
#pragma unroll
    for (int rq = 0; rq < 4; ++rq) {
      us4 o;
#pragma unroll
      for (int r = 0; r < 4; ++r) o[r] = f2bf(oacc[vb2][rq * 4 + r] * inv);
      *(us4*)(orow + vb2 * 32 + rq * 8 + rc4) = o;
    }
}

extern "C" void kernel_launch(void* const* d_in, const int* in_sizes, int n_in,
                              void* d_out, int out_size, void* d_ws,
                              size_t ws_size, hipStream_t stream) {
  const float* x = (const float*)d_in[0];      // [B,S,E]
  const float* w_qkv = (const float*)d_in[1];  // [E,3E]
  const float* b_qkv = (const float*)d_in[2];  // [3E]
  const float* w_out = (const float*)d_in[3];  // [E,E]
  const float* b_out = (const float*)d_in[4];  // [E]
  float* out = (float*)d_out;                  // [B,S,E] fp32

  const size_t per = (size_t)BATCH * NH * SEQ * HD;  // 6291456
  ushort_t* q_buf = (ushort_t*)d_ws;          // [B,H,S,D] (scaled by QSCALE)
  ushort_t* k_buf = q_buf + per;              // [B,H,S,D]
  ushort_t* v_buf = k_buf + per;              // [B,H,D,S] (transposed)
  ushort_t* attn_buf = v_buf + per;           // [B,S,E] bf16
  ushort_t* xb = attn_buf + per;              // [M,E] bf16
  ushort_t* wqkvT = xb + per;                 // [3E,E] bf16
  ushort_t* woutT = wqkvT + (size_t)N3E * EMBED;  // [E,E] bf16

  convert_x<<<(MROWS * EMBED) / 2048, 256, 0, stream>>>(x, xb);
  transpose_w<<<dim3(N3E / 64, EMBED / 64), 256, 0, stream>>>(w_qkv, wqkvT,
                                                              EMBED, N3E);
  transpose_w<<<dim3(EMBED / 64, EMBED / 64), 256, 0, stream>>>(w_out, woutT,
                                                                EMBED, EMBED);

  dim3 g1(N3E / 128, MROWS / 128);  // (18,64) = 1152 blocks
  gemm_mfma<N3E, EMBED, true><<<g1, 256, 0, stream>>>(
      xb, wqkvT, b_qkv, nullptr, q_buf, k_buf, v_buf);

  dim3 g2(BATCH * NH, 32);  // bh fast (XCD = bh%8); stratified qt2 map
  flash_mfma<<<g2, 256, 0, stream>>>(q_buf, k_buf, v_buf, attn_buf);

  dim3 g3(EMBED / 128, MROWS / 128);  // (6,64) = 384 blocks
  gemm_mfma<EMBED, EMBED, false><<<g3, 256, 0, stream>>>(
      attn_buf, woutT, b_out, out, nullptr, nullptr, nullptr);
}

// Round 11
// 222.967 us; speedup vs baseline: 1.3535x; 1.0285x over previous
//
#include <hip/hip_runtime.h>

#define EMBED 768
#define NH 12
#define HD 64
#define SEQ 4096
#define BATCH 2
#define MROWS (BATCH * SEQ)   // 8192
#define N3E (3 * EMBED)       // 2304

typedef short bf16x8 __attribute__((ext_vector_type(8)));  // 8 bf16 = 4 VGPRs
typedef float fx4 __attribute__((ext_vector_type(4)));     // MFMA C/D 16x16
typedef float f32x16 __attribute__((ext_vector_type(16))); // MFMA C/D 32x32
typedef unsigned short ushort_t;
typedef unsigned short us4 __attribute__((ext_vector_type(4)));  // 8B packed

#if __has_builtin(__builtin_amdgcn_exp2f)
#define EXP2F(x) __builtin_amdgcn_exp2f(x)
#else
#define EXP2F(x) exp2f(x)
#endif

// Q pre-scale: (1/sqrt(64)) * log2(e)  -> softmax runs in exp2 domain
#define QSCALE 0.18033688011112042f

// fp32 -> bf16 round-to-nearest-even
__device__ inline ushort_t f2bf(float f) {
  union { float f; unsigned int u; } x; x.f = f;
  unsigned int r = x.u + 0x7fffu + ((x.u >> 16) & 1u);
  return (ushort_t)(r >> 16);
}

// v_cvt_pk_bf16_f32 (no builtin on gfx950)
__device__ inline unsigned int cvtpk(float a, float b) {
  unsigned int r;
  asm("v_cvt_pk_bf16_f32 %0, %1, %2" : "=v"(r) : "v"(a), "v"(b));
  return r;
}
// v_permlane32_swap_b32: x[hi lanes] <-> y[lo lanes]
__device__ inline void plswap(unsigned int& x, unsigned int& y) {
  asm("v_permlane32_swap_b32 %0, %1" : "+v"(x), "+v"(y));
}

// ---------------------------------------------------------------------------
// x [M,K] fp32 -> bf16, straight copy. 8 elems/thread.
// ---------------------------------------------------------------------------
__global__ __launch_bounds__(256) void convert_x(const float* __restrict__ in,
                                                 ushort_t* __restrict__ out) {
  int i = (blockIdx.x * 256 + threadIdx.x) * 8;
  float4 a = *(const float4*)(in + i);
  float4 b = *(const float4*)(in + i + 4);
  bf16x8 o;
  o[0] = f2bf(a.x); o[1] = f2bf(a.y); o[2] = f2bf(a.z); o[3] = f2bf(a.w);
  o[4] = f2bf(b.x); o[5] = f2bf(b.y); o[6] = f2bf(b.z); o[7] = f2bf(b.w);
  *(bf16x8*)(out + i) = o;
}

// ---------------------------------------------------------------------------
// W [K,N] fp32 -> W^T [N,K] bf16 via 64x64 LDS tile (stride 65: conflict-free)
// ---------------------------------------------------------------------------
__global__ __launch_bounds__(256) void transpose_w(const float* __restrict__ in,
                                                   ushort_t* __restrict__ out,
                                                   int K, int N) {
  __shared__ float t[64][65];
  const int bn = blockIdx.x * 64, bk = blockIdx.y * 64;
  const int c = threadIdx.x & 63, r0 = threadIdx.x >> 6;
#pragma unroll
  for (int rr = 0; rr < 16; ++rr) {
    int row = rr * 4 + r0;
    t[row][c] = in[(size_t)(bk + row) * N + bn + c];
  }
  __syncthreads();
#pragma unroll
  for (int rr = 0; rr < 16; ++rr) {
    int row = rr * 4 + r0;
    out[(size_t)(bn + row) * K + bk + c] = f2bf(t[c][row]);
  }
}

// ---------------------------------------------------------------------------
// bf16 MFMA GEMM v4 (unchanged from R10: proven -27 us): m97 128x128 K-loop
// (triple-buffer, counted vmcnt(4), one barrier/K-step, XCD swizzle,
// sched_barrier fences) + V-epilogue LDS-transpose (coalesced [B,H,D,S]).
// ---------------------------------------------------------------------------
template <int N_, int K_, bool SCATTER>
__global__ __launch_bounds__(256) void gemm_mfma(
    const ushort_t* __restrict__ A, const ushort_t* __restrict__ Bt,
    const float* __restrict__ bias, float* __restrict__ outF,
    ushort_t* __restrict__ oq, ushort_t* __restrict__ ok,
    ushort_t* __restrict__ ov) {
  constexpr int NT = K_ / 32;  // 24
  __shared__ __align__(16) ushort_t smem[24576];  // 48 KB: As[3]|Bs[3], reused
  ushort_t* As_ = smem;            // [3][128*32]
  ushort_t* Bs_ = smem + 12288;    // [3][128*32]
  const int tid = threadIdx.x;
  const int w = tid >> 6, lane = tid & 63;
  const int quad = lane >> 4, ln = lane & 15;

  // ---- bijective XCD swizzle (nwg % 8 == 0 for both grids) ----
  const int gx = gridDim.x;
  const int nwg = gx * gridDim.y;
  int lin = blockIdx.y * gx + blockIdx.x;
  lin = (lin & 7) * (nwg >> 3) + (lin >> 3);
  const int bm = (lin / gx) * 128, bn = (lin % gx) * 128;

  const int wm = (w >> 1) * 64, wn = (w & 1) * 64;
  const int sr = lane >> 2;     // row within 16-row chunk
  const int sslot = lane & 3;   // 16B slot within row

  auto STAGE = [&](int ti, int b) {
#pragma unroll
    for (int r = 0; r < 2; ++r) {
      const int c = w + r * 4;        // chunk 0..7 (wave-uniform)
      const int m = c * 16 + sr;      // tile row 0..127
      const int kk = ti * 32 + ((sslot ^ (m & 3)) << 3);
      __builtin_amdgcn_global_load_lds(
          (const __attribute__((address_space(1))) unsigned int*)
              (A + (size_t)(bm + m) * K_ + kk),
          (__attribute__((address_space(3))) unsigned int*)(As_ + b * 4096 + c * 512),
          16, 0, 0);
      __builtin_amdgcn_global_load_lds(
          (const __attribute__((address_space(1))) unsigned int*)
              (Bt + (size_t)(bn + m) * K_ + kk),
          (__attribute__((address_space(3))) unsigned int*)(Bs_ + b * 4096 + c * 512),
          16, 0, 0);
    }
  };

  fx4 acc[4][4] = {};

  auto COMPUTE = [&](int b) {
    bf16x8 af[4], bfr[4];
#pragma unroll
    for (int i = 0; i < 4; ++i) {
      const int m = wm + i * 16 + ln;
      af[i] = *(const bf16x8*)(As_ + b * 4096 + m * 32 + ((quad ^ (m & 3)) << 3));
    }
#pragma unroll
    for (int j = 0; j < 4; ++j) {
      const int n = wn + j * 16 + ln;
      bfr[j] = *(const bf16x8*)(Bs_ + b * 4096 + n * 32 + ((quad ^ (n & 3)) << 3));
    }
#pragma unroll
    for (int i = 0; i < 4; ++i)
#pragma unroll
      for (int j = 0; j < 4; ++j)
        acc[i][j] = __builtin_amdgcn_mfma_f32_16x16x32_bf16(af[i], bfr[j],
                                                            acc[i][j], 0, 0, 0);
  };

  // ---- prologue: stage tiles 0,1 ----
  STAGE(0, 0);
  STAGE(1, 1);

  int bufR = 0;
  for (int t = 0; t < NT - 2; ++t) {
    asm volatile("s_waitcnt vmcnt(4)" ::: "memory");  // tile t landed (this wave)
    __builtin_amdgcn_s_barrier();                      // cross-wave publish
    __builtin_amdgcn_sched_barrier(0);                 // no motion across
    const int bufS = (bufR >= 1) ? bufR - 1 : 2;       // (t+2)%3 == (t-1)%3
    STAGE(t + 2, bufS);
    COMPUTE(bufR);
    bufR = (bufR < 2) ? bufR + 1 : 0;
  }
  // t = NT-2: tiles NT-2, NT-1 outstanding -> vmcnt(4) waits for NT-2
  asm volatile("s_waitcnt vmcnt(4)" ::: "memory");
  __builtin_amdgcn_s_barrier();
  __builtin_amdgcn_sched_barrier(0);
  COMPUTE(bufR);
  bufR = (bufR < 2) ? bufR + 1 : 0;
  // t = NT-1: only 4 outstanding -> must drain fully
  asm volatile("s_waitcnt vmcnt(0)" ::: "memory");
  __builtin_amdgcn_s_barrier();
  __builtin_amdgcn_sched_barrier(0);
  COMPUTE(bufR);

  // ---- epilogue ----
  if (!SCATTER) {
#pragma unroll
    for (int j = 0; j < 4; ++j) {
      const int n = bn + wn + j * 16 + ln;
      const float bv = bias[n];
#pragma unroll
      for (int i = 0; i < 4; ++i) {
        const int m0 = bm + wm + i * 16 + quad * 4;
#pragma unroll
        for (int r = 0; r < 4; ++r)
          outF[(size_t)(m0 + r) * N_ + n] = acc[i][j][r] + bv;
      }
    }
  } else {
    const int t3 = bn / EMBED;  // 768 % 128 == 0: whole tile in one of q/k/v
    if (t3 == 2) {
      // ---- V: LDS-transpose -> coalesced [B,H,D,S] bf16x8 writes ----
      __syncthreads();  // all waves' K-loop LDS reads complete
#pragma unroll
      for (int j = 0; j < 4; ++j) {
        const int nl = wn + j * 16 + ln;        // local n (0..127)
        const float bv = bias[bn + nl];
        const int key = (nl & 7) << 4;          // XOR bank-spread (x16 elems)
#pragma unroll
        for (int i = 0; i < 4; ++i) {
          const int m0 = wm + i * 16 + quad * 4;
#pragma unroll
          for (int r = 0; r < 4; ++r)
            smem[nl * 128 + ((m0 + r) ^ key)] = f2bf(acc[i][j][r] + bv);
        }
      }
      __syncthreads();
      const int b_ = bm >> 12, s0 = bm & 4095;
      const int lr = lane >> 4;   // row-within-group (0..3)
      const int lc = lane & 15;   // 16B chunk within 256B row
#pragma unroll
      for (int it = 0; it < 8; ++it) {
        const int nl = w * 32 + it * 4 + lr;    // local n (0..127)
        const int rem = bn + nl - 2 * EMBED;
        const int h = rem >> 6, d = rem & 63;
        const int mc = lc * 8;                  // logical m chunk (8 elems)
        bf16x8 val =
            *(const bf16x8*)&smem[nl * 128 + (mc ^ ((nl & 7) << 4))];
        *(bf16x8*)&ov[((size_t)(b_ * NH + h) * HD + d) * SEQ + s0 + mc] = val;
      }
    } else {
      // ---- Q/K: direct stores (32B/quad segments, line-combined in L2) ----
#pragma unroll
      for (int j = 0; j < 4; ++j) {
        const int nn = bn + wn + j * 16 + ln;
        const int rem = nn - t3 * EMBED;
        const int h = rem >> 6, d = rem & 63;
        const float bv = bias[nn];
#pragma unroll
        for (int i = 0; i < 4; ++i) {
          const int m0 = bm + wm + i * 16 + quad * 4;
#pragma unroll
          for (int r = 0; r < 4; ++r) {
            const int m = m0 + r;
            const int b_ = m >> 12, s = m & 4095;
            const float v = acc[i][j][r] + bv;
            if (t3 == 0)
              oq[((size_t)(b_ * NH + h) * SEQ + s) * HD + d] = f2bf(v * QSCALE);
            else
              ok[((size_t)(b_ * NH + h) * SEQ + s) * HD + d] = f2bf(v);
          }
        }
      }
    }
  }
}

// ---------------------------------------------------------------------------
// Causal flash attention v7: 2x2 WAVE GRID (qh = w&1 q-half, kh = w>>1
// kr-half) -- DS traffic halved vs v3.
//  * R10 analysis: flash at 2x DS floor; per-iter wall = DS+MFMA+VALU summed
//    (lockstep).  v3's 4 waves read IDENTICAL kf/vf frags (4x redundant DS).
//  * Fixed-shift softmax is LINEAR (no running max): l = sum p, O = sum V.P
//    -> kr splits across waves with one final reduction.  Per wave: 4 kf +
//    4 vf b128 (each shared by 2 q-cols) = 8 reads/iter vs 16; MFMA count
//    unchanged (8 QK + 8 PV).
//  * Mask by rel = (kt-ktd0)*64 + kh*32 - qh*64: rel<0 none; 0 -> strA;
//    32 -> deadA+strB; >=64 -> skip wave entirely (4 of 8 diag slots).
//  * Final: kh=1 waves dump oacc+l partials into dead K/V LDS (33 KB total,
//    conflict-free column writes), kh=0 waves add + epilogue.  Once/block.
//  * launch_bounds(256,3): VGPR headroom (oacc 64 + qf 32), no spill;
//    measured time-avg occupancy (~6 waves/CU) was below the old cap anyway.
// ---------------------------------------------------------------------------
__global__ __launch_bounds__(256, 3) void flash_mfma(
    const ushort_t* __restrict__ qb, const ushort_t* __restrict__ kb,
    const ushort_t* __restrict__ vb, ushort_t* __restrict__ attn) {
  // [Ks 2x8KB][Vt 2x8KB][lred 1KB] = 33792 B; K/V region reused as O-reduce
  __shared__ __align__(16) ushort_t smemAll[16896];

  const int tid = threadIdx.x;
  const int w = tid >> 6;
  const int lane = tid & 63;
  const int r32 = lane & 31;   // MFMA row / q-col index
  const int hf = lane >> 5;    // lane half
  const int gk = r32 & 7;      // granule swizzle key
  const int rc4 = hf * 4;      // rowcode offset
  const int qh = w & 1;        // q-half (0: q 0-63, 1: q 64-127)
  const int kh = w >> 1;       // kr-half (0: kr 0-31, 1: kr 32-63)

  const int bh = blockIdx.x;   // 0..23 (fast dim, 24%8==0 -> XCD = bh%8)
  const int y = blockIdx.y;    // 0..31
  const int qt2 = (y < 11) ? (31 - y) : (y - 11);  // stratified map
  const int ktd0 = 2 * qt2;    // first diag-zone k-tile
  const int nkt = 2 * qt2 + 2;

  const size_t base = (size_t)bh * SEQ * HD;
  const ushort_t* Qg = qb + base;
  const ushort_t* Kg = kb + base;
  const ushort_t* Vg = vb + base;  // [HD][SEQ]

  // ---- staging geometry (identical to v3; by wave id) ----
  const int srow = lane >> 3;
  const int sg = (lane & 7) ^ srow;
  const int row0 = w * 8 + srow;
  const ushort_t* kp = Kg + (size_t)row0 * HD + (sg << 3);
  const ushort_t* vp = Vg + (size_t)row0 * SEQ + (sg << 3);

  // ---- Q fragments: two 32-col groups within this wave's q-half ----
  const int qbase = qt2 * 128 + qh * 64 + r32;
  bf16x8 qfA[4], qfB[4];
  {
    const ushort_t* qra = Qg + (size_t)qbase * HD;
    const ushort_t* qrb = qra + (size_t)32 * HD;
#pragma unroll
    for (int dc = 0; dc < 4; ++dc) {
      qfA[dc] = *(const bf16x8*)(qra + dc * 16 + hf * 8);
      qfB[dc] = *(const bf16x8*)(qrb + dc * 16 + hf * 8);
    }
  }

  f32x16 oacc[2][2] = {};  // [qcol][vblk], O^T partial over this kr-half
  float lsumA = 0.f, lsumB = 0.f;

  // ---- prologue: stage kt=0 into buf 0 ----
#pragma unroll
  for (int r2 = 0; r2 < 2; ++r2) {
    __builtin_amdgcn_global_load_lds(
        (const __attribute__((address_space(1))) unsigned int*)(kp + r2 * (32 * HD)),
        (__attribute__((address_space(3))) unsigned int*)(smemAll + (w + r2 * 4) * 512),
        16, 0, 0);
    __builtin_amdgcn_global_load_lds(
        (const __attribute__((address_space(1))) unsigned int*)(vp + r2 * (32 * SEQ)),
        (__attribute__((address_space(3))) unsigned int*)(smemAll + 8192 + (w + r2 * 4) * 512),
        16, 0, 0);
  }
  kp += 64 * HD;
  vp += 64;

  for (int kt = 0; kt < nkt; ++kt) {
    const int cur = kt & 1;
    __syncthreads();  // publish buf `cur` (drains in-flight DMA)
    if (kt + 1 < nkt) {
      const int nxt = cur ^ 1;
#pragma unroll
      for (int r2 = 0; r2 < 2; ++r2) {
        __builtin_amdgcn_global_load_lds(
            (const __attribute__((address_space(1))) unsigned int*)(kp + r2 * (32 * HD)),
            (__attribute__((address_space(3))) unsigned int*)(smemAll + nxt * 4096 + (w + r2 * 4) * 512),
            16, 0, 0);
        __builtin_amdgcn_global_load_lds(
            (const __attribute__((address_space(1))) unsigned int*)(vp + r2 * (32 * SEQ)),
            (__attribute__((address_space(3))) unsigned int*)(smemAll + 8192 + nxt * 4096 + (w + r2 * 4) * 512),
            16, 0, 0);
      }
      kp += 64 * HD;
      vp += 64;
    }

    // rel: this wave's kr-block position vs its q-window (diag zone only)
    int rel = -64;
    if (kt >= ktd0) rel = (kt - ktd0) * 64 + kh * 32 - qh * 64;
    if (rel >= 64) continue;  // both q-cols fully masked (wave-uniform)

    const ushort_t* Kc = smemAll + cur * 4096;
    const ushort_t* Vc = smemAll + 8192 + cur * 4096;
    const int krow = (kh * 32 + r32) * 64;

    // ---- QK^T: two q-cols share each kf (interleaved chains) ----
    f32x16 sA = {}, sB = {};
#pragma unroll
    for (int dc = 0; dc < 4; ++dc) {
      bf16x8 kf = *(const bf16x8*)(Kc + krow + (((2 * dc + hf) ^ gk) << 3));
      sA = __builtin_amdgcn_mfma_f32_32x32x16_bf16(kf, qfA[dc], sA, 0, 0, 0);
      sB = __builtin_amdgcn_mfma_f32_32x32x16_bf16(kf, qfB[dc], sB, 0, 0, 0);
    }
    // ---- causal mask (rel == 0: straddle A; rel == 32: dead A, straddle B)
    if (rel == 0) {
#pragma unroll
      for (int r = 0; r < 16; ++r) {
        const int rowc = (r & 3) + 8 * (r >> 2) + rc4;
        if (rowc > r32) sA[r] = -1e30f;
      }
    } else if (rel == 32) {
#pragma unroll
      for (int r = 0; r < 16; ++r) {
        const int rowc = (r & 3) + 8 * (r >> 2) + rc4;
        sA[r] = -1e30f;
        if (rowc > r32) sB[r] = -1e30f;
      }
    }
    // ---- exp2 + l (pairwise trees) ----
    float eA[16], eB[16];
#pragma unroll
    for (int r = 0; r < 16; ++r) {
      eA[r] = EXP2F(sA[r]);
      eB[r] = EXP2F(sB[r]);
    }
    {
      float a0 = ((eA[0] + eA[1]) + (eA[2] + eA[3])) +
                 ((eA[4] + eA[5]) + (eA[6] + eA[7]));
      float a1 = ((eA[8] + eA[9]) + (eA[10] + eA[11])) +
                 ((eA[12] + eA[13]) + (eA[14] + eA[15]));
      lsumA += a0 + a1;
      float b0 = ((eB[0] + eB[1]) + (eB[2] + eB[3])) +
                 ((eB[4] + eB[5]) + (eB[6] + eB[7]));
      float b1 = ((eB[8] + eB[9]) + (eB[10] + eB[11])) +
                 ((eB[12] + eB[13]) + (eB[14] + eB[15]));
      lsumB += b0 + b1;
    }
    // ---- pack + PV per 16-kr chunk; vf shared by both q-cols ----
    __builtin_amdgcn_s_setprio(1);
#pragma unroll
    for (int ch = 0; ch < 2; ++ch) {
      const int rb = ch * 8;
      unsigned int ax0 = cvtpk(eA[rb + 0], eA[rb + 1]);
      unsigned int ax1 = cvtpk(eA[rb + 2], eA[rb + 3]);
      unsigned int ay0 = cvtpk(eA[rb + 4], eA[rb + 5]);
      unsigned int ay1 = cvtpk(eA[rb + 6], eA[rb + 7]);
      plswap(ax0, ay0);
      plswap(ax1, ay1);
      union { unsigned int u[4]; bf16x8 v; } pfA;
      pfA.u[0] = ax0; pfA.u[1] = ax1; pfA.u[2] = ay0; pfA.u[3] = ay1;
      unsigned int bx0 = cvtpk(eB[rb + 0], eB[rb + 1]);
      unsigned int bx1 = cvtpk(eB[rb + 2], eB[rb + 3]);
      unsigned int by0 = cvtpk(eB[rb + 4], eB[rb + 5]);
      unsigned int by1 = cvtpk(eB[rb + 6], eB[rb + 7]);
      plswap(bx0, by0);
      plswap(bx1, by1);
      union { unsigned int u[4]; bf16x8 v; } pfB;
      pfB.u[0] = bx0; pfB.u[1] = bx1; pfB.u[2] = by0; pfB.u[3] = by1;
      const int c = kh * 2 + ch;  // global 16-kr chunk index
#pragma unroll
      for (int vb2 = 0; vb2 < 2; ++vb2) {
        bf16x8 vf = *(const bf16x8*)(Vc + (vb2 * 32 + r32) * 64 +
                                     (((2 * c + hf) ^ gk) << 3));
        oacc[0][vb2] =
            __builtin_amdgcn_mfma_f32_32x32x16_bf16(vf, pfA.v, oacc[0][vb2], 0, 0, 0);
        oacc[1][vb2] =
            __builtin_amdgcn_mfma_f32_32x32x16_bf16(vf, pfB.v, oacc[1][vb2], 0, 0, 0);
      }
    }
    __builtin_amdgcn_s_setprio(0);
  }

  // ---- cross-wave reduction (kr-halves) + epilogue ----
  lsumA += __shfl_xor(lsumA, 32);  // fold hf within wave
  lsumB += __shfl_xor(lsumB, 32);
  __syncthreads();                  // K/V region now dead everywhere
  float* ored = (float*)smemAll;                 // 8192 floats (32 KB)
  float* lred = (float*)(smemAll + 16384);       // 256 floats (1 KB)
  if (kh == 1) {                    // upper kr-half: dump partials
    float* ob = ored + qh * 4096;
#pragma unroll
    for (int qc = 0; qc < 2; ++qc)
#pragma unroll
      for (int vb2 = 0; vb2 < 2; ++vb2)
#pragma unroll
        for (int r = 0; r < 16; ++r)
          ob[((qc * 2 + vb2) * 16 + r) * 64 + lane] = oacc[qc][vb2][r];
    lred[qh * 128 + lane] = lsumA;
    lred[qh * 128 + 64 + lane] = lsumB;
  }
  __syncthreads();
  if (kh == 0) {                    // lower kr-half: add + write out
    float* ob = ored + qh * 4096;
#pragma unroll
    for (int qc = 0; qc < 2; ++qc)
#pragma unroll
      for (int vb2 = 0; vb2 < 2; ++vb2)
#pragma unroll
        for (int r = 0; r < 16; ++r)
          oacc[qc][vb2][r] += ob[((qc * 2 + vb2) * 16 + r) * 64 + lane];
    lsumA += lred[qh * 128 + lane];
    lsumB += lred[qh * 128 + 64 + lane];
    const int b_ = bh / NH, h = bh % NH;
#pragma unroll
    for (int qc = 0; qc < 2; ++qc) {
      const float inv = 1.f / (qc ? lsumB : lsumA);
      ushort_t* orow = attn +
          (size_t)(b_ * SEQ + qt2 * 128 + qh * 64 + qc * 32 + r32) * EMBED +
          h * HD;
#pragma unroll
      for (int vb2 = 0; vb2 < 2; ++vb2)
#pragma unroll
        for (int rq = 0; rq < 4; ++rq) {
          us4 o;
#pragma unroll
          for (int r = 0; r < 4; ++r)
            o[r] = f2bf(oacc[qc][vb2][rq * 4 + r] * inv);
          *(us4*)(orow + vb2 * 32 + rq * 8 + rc4) = o;
        }
    }
  }
}

extern "C" void kernel_launch(void* const* d_in, const int* in_sizes, int n_in,
                              void* d_out, int out_size, void* d_ws,
                              size_t ws_size, hipStream_t stream) {
  const float* x = (const float*)d_in[0];      // [B,S,E]
  const float* w_qkv = (const float*)d_in[1];  // [E,3E]
  const float* b_qkv = (const float*)d_in[2];  // [3E]
  const float* w_out = (const float*)d_in[3];  // [E,E]
  const float* b_out = (const float*)d_in[4];  // [E]
  float* out = (float*)d_out;                  // [B,S,E] fp32

  const size_t per = (size_t)BATCH * NH * SEQ * HD;  // 6291456
  ushort_t* q_buf = (ushort_t*)d_ws;          // [B,H,S,D] (scaled by QSCALE)
  ushort_t* k_buf = q_buf + per;              // [B,H,S,D]
  ushort_t* v_buf = k_buf + per;              // [B,H,D,S] (transposed)
  ushort_t* attn_buf = v_buf + per;           // [B,S,E] bf16
  ushort_t* xb = attn_buf + per;              // [M,E] bf16
  ushort_t* wqkvT = xb + per;                 // [3E,E] bf16
  ushort_t* woutT = wqkvT + (size_t)N3E * EMBED;  // [E,E] bf16

  convert_x<<<(MROWS * EMBED) / 2048, 256, 0, stream>>>(x, xb);
  transpose_w<<<dim3(N3E / 64, EMBED / 64), 256, 0, stream>>>(w_qkv, wqkvT,
                                                              EMBED, N3E);
  transpose_w<<<dim3(EMBED / 64, EMBED / 64), 256, 0, stream>>>(w_out, woutT,
                                                                EMBED, EMBED);

  dim3 g1(N3E / 128, MROWS / 128);  // (18,64) = 1152 blocks
  gemm_mfma<N3E, EMBED, true><<<g1, 256, 0, stream>>>(
      xb, wqkvT, b_qkv, nullptr, q_buf, k_buf, v_buf);

  dim3 g2(BATCH * NH, 32);  // bh fast (XCD = bh%8); stratified qt2 map
  flash_mfma<<<g2, 256, 0, stream>>>(q_buf, k_buf, v_buf, attn_buf);

  dim3 g3(EMBED / 128, MROWS / 128);  // (6,64) = 384 blocks
  gemm_mfma<EMBED, EMBED, false><<<g3, 256, 0, stream>>>(
      attn_buf, woutT, b_out, out, nullptr, nullptr, nullptr);
}